// Round 1
// baseline (518.865 us; speedup 1.0000x reference)
//
#include <hip/hip_runtime.h>

#define NN 1024
#define FIN 512
#define HH1 256
#define HH2 128
#define MTOT 32768   // B*N total rows

typedef unsigned short ushort_t;
using bf16x8 = __attribute__((ext_vector_type(8))) short;
using f32x4  = __attribute__((ext_vector_type(4))) float;

__device__ __forceinline__ float leakyf(float x) { return fmaxf(x, 0.01f * x); }
__device__ __forceinline__ float eluf(float x) { return x > 0.0f ? x : __expf(x) - 1.0f; }
// pack the high halves of two fp32 bit patterns: [u1.hi : u0.hi]
__device__ __forceinline__ unsigned pack_hi(unsigned u0, unsigned u1) {
  return __builtin_amdgcn_perm(u1, u0, 0x07060302u);
}
// trunc-split two fp32 -> bf16 hi pair + bf16 lo pair (lo compensates hi trunc)
__device__ __forceinline__ void split_pack2(float f0, float f1, unsigned& hp, unsigned& lp) {
  unsigned u0 = __float_as_uint(f0), u1 = __float_as_uint(f1);
  hp = pack_hi(u0, u1);
  float l0 = f0 - __uint_as_float(u0 & 0xFFFF0000u);
  float l1 = f1 - __uint_as_float(u1 & 0xFFFF0000u);
  lp = pack_hi(__float_as_uint(l0), __float_as_uint(l1));
}
// RNE-round two fp32 to bf16 and pack
__device__ __forceinline__ unsigned pack_rne(float f0, float f1) {
  unsigned u0 = __float_as_uint(f0); u0 += 0x7FFFu + ((u0 >> 16) & 1u);
  unsigned u1 = __float_as_uint(f1); u1 += 0x7FFFu + ((u1 >> 16) & 1u);
  return pack_hi(u0, u1);
}

// ---------------------------------------------------------------------------
// W[K][N] fp32 -> WT[N][K] trunc-split bf16. K = 1<<kshift.
// ---------------------------------------------------------------------------
__global__ __launch_bounds__(256) void transpose_w_split(const float* __restrict__ W,
                                                         ushort_t* __restrict__ WThi,
                                                         ushort_t* __restrict__ WTlo,
                                                         int Nc, int kshift) {
  int idx = blockIdx.x * 256 + threadIdx.x;
  int k = idx & ((1 << kshift) - 1);
  int n = idx >> kshift;
  float f = W[(size_t)k * Nc + n];
  unsigned u = __float_as_uint(f);
  WThi[idx] = (ushort_t)(u >> 16);
  float lo = f - __uint_as_float(u & 0xFFFF0000u);
  WTlo[idx] = (ushort_t)(__float_as_uint(lo) >> 16);
}

// ---------------------------------------------------------------------------
// Producer GEMM, full split precision (3 MFMA): C = A(fp32)[M,K] @ B, with
// B transposed split BT[NC][K]. In-kernel trunc-split of A. Block tile
// 64 x NC (y=1: each block sees full output rows). Outputs:
//   CT split [NC][MTOT]  (B-operand for the attention GEMM)
//   el/er row dots vs avec[0:NC]/avec[NC:2NC] from the fp32 accumulators,
//   reduced in-wave and atomicAdd'ed (el/er pre-zeroed).
// K-loop is register-prefetched (T3-lite 2-phase): tile k+1's global loads
// issue BEFORE tile k's ds_read+MFMA, so HBM/L2 latency drains under compute.
// ---------------------------------------------------------------------------
template<int NC>
__global__ __launch_bounds__(256) void gemm_asplit(const float* __restrict__ A,
                                                   const ushort_t* __restrict__ BThi,
                                                   const ushort_t* __restrict__ BTlo,
                                                   const float* __restrict__ avec,
                                                   ushort_t* __restrict__ CThi,
                                                   ushort_t* __restrict__ CTlo,
                                                   float* __restrict__ el,
                                                   float* __restrict__ er, int K) {
  constexpr int NFR = NC / 32;   // n-frags per wave (wave tile 32 x NC/2)
  constexpr int NB  = NC / 64;   // 16B B-chunks per thread per buffer
  __shared__ ushort_t Ah[64 * 40], Al[64 * 40];
  __shared__ ushort_t Bh[NC * 40], Bl[NC * 40];
  __shared__ float aL[NC], aR[NC];
  const int t = threadIdx.x, lane = t & 63, wid = t >> 6;
  const int wm = (wid & 1) * 32, wn = (wid >> 1) * (NC / 2);
  const int ln = lane & 15, quad = lane >> 4;
  const int m0 = blockIdx.x * 64;
  if (t < NC) { aL[t] = avec[t]; aR[t] = avec[NC + t]; }
  const int ra = t >> 2, ka = (t & 3) * 8;
  const float* ap = A + (size_t)(m0 + ra) * K + ka;
  const int brow = (t >> 2);            // + i*64 per chunk
  const int bko  = (t & 3) * 8;
  f32x4 acc[2][NFR];
#pragma unroll
  for (int mi = 0; mi < 2; ++mi)
#pragma unroll
    for (int ni = 0; ni < NFR; ++ni) acc[mi][ni] = (f32x4){0.f, 0.f, 0.f, 0.f};

  // ---- prologue: prefetch tile k0=0 into registers
  float4 fa0 = *(const float4*)(ap);
  float4 fa1 = *(const float4*)(ap + 4);
  uint4 vbh[NB], vbl[NB];
#pragma unroll
  for (int i = 0; i < NB; ++i) {
    size_t off = (size_t)(brow + i * 64) * K + bko;
    vbh[i] = *(const uint4*)&BThi[off];
    vbl[i] = *(const uint4*)&BTlo[off];
  }

  for (int k0 = 0; k0 < K; k0 += 32) {
    uint4 ah4, al4;
    split_pack2(fa0.x, fa0.y, ah4.x, al4.x);
    split_pack2(fa0.z, fa0.w, ah4.y, al4.y);
    split_pack2(fa1.x, fa1.y, ah4.z, al4.z);
    split_pack2(fa1.z, fa1.w, ah4.w, al4.w);
    __syncthreads();
    *(uint4*)&Ah[ra * 40 + ka] = ah4;
    *(uint4*)&Al[ra * 40 + ka] = al4;
#pragma unroll
    for (int i = 0; i < NB; ++i) {
      *(uint4*)&Bh[(brow + i * 64) * 40 + bko] = vbh[i];
      *(uint4*)&Bl[(brow + i * 64) * 40 + bko] = vbl[i];
    }
    __syncthreads();
    // ---- issue NEXT tile's global loads now (clamped, branchless) so they
    // are in flight across the ds_read+MFMA cluster below.
    const int kn = (k0 + 32 < K) ? (k0 + 32) : 0;
    fa0 = *(const float4*)(ap + kn);
    fa1 = *(const float4*)(ap + kn + 4);
#pragma unroll
    for (int i = 0; i < NB; ++i) {
      size_t off = (size_t)(brow + i * 64) * K + kn + bko;
      vbh[i] = *(const uint4*)&BThi[off];
      vbl[i] = *(const uint4*)&BTlo[off];
    }
    bf16x8 ahf[2], alf[2], bhf[NFR], blf[NFR];
#pragma unroll
    for (int i = 0; i < 2; ++i) {
      const int ao = (wm + i * 16 + ln) * 40 + quad * 8;
      ahf[i] = *(const bf16x8*)&Ah[ao];
      alf[i] = *(const bf16x8*)&Al[ao];
    }
#pragma unroll
    for (int i = 0; i < NFR; ++i) {
      const int bo = (wn + i * 16 + ln) * 40 + quad * 8;
      bhf[i] = *(const bf16x8*)&Bh[bo];
      blf[i] = *(const bf16x8*)&Bl[bo];
    }
#pragma unroll
    for (int mi = 0; mi < 2; ++mi)
#pragma unroll
      for (int ni = 0; ni < NFR; ++ni) {
        acc[mi][ni] = __builtin_amdgcn_mfma_f32_16x16x32_bf16(ahf[mi], bhf[ni], acc[mi][ni], 0, 0, 0);
        acc[mi][ni] = __builtin_amdgcn_mfma_f32_16x16x32_bf16(ahf[mi], blf[ni], acc[mi][ni], 0, 0, 0);
        acc[mi][ni] = __builtin_amdgcn_mfma_f32_16x16x32_bf16(alf[mi], bhf[ni], acc[mi][ni], 0, 0, 0);
      }
  }
#pragma unroll
  for (int mi = 0; mi < 2; ++mi) {
    const int mr = m0 + wm + mi * 16 + quad * 4;
#pragma unroll
    for (int ni = 0; ni < NFR; ++ni) {
      const int c = wn + ni * 16 + ln;
      unsigned h01, l01, h23, l23;
      split_pack2(acc[mi][ni][0], acc[mi][ni][1], h01, l01);
      split_pack2(acc[mi][ni][2], acc[mi][ni][3], h23, l23);
      *(uint2*)&CThi[(size_t)c * MTOT + mr] = make_uint2(h01, h23);
      *(uint2*)&CTlo[(size_t)c * MTOT + mr] = make_uint2(l01, l23);
    }
#pragma unroll
    for (int rr = 0; rr < 4; ++rr) {
      float vel = 0.f, ver = 0.f;
#pragma unroll
      for (int ni = 0; ni < NFR; ++ni) {
        const int c = wn + ni * 16 + ln;
        vel = fmaf(acc[mi][ni][rr], aL[c], vel);
        ver = fmaf(acc[mi][ni][rr], aR[c], ver);
      }
#pragma unroll
      for (int m = 1; m < 16; m <<= 1) {
        vel += __shfl_xor(vel, m);
        ver += __shfl_xor(ver, m);
      }
      if (ln == 0) {
        atomicAdd(&el[mr + rr], vel);
        atomicAdd(&er[mr + rr], ver);
      }
    }
  }
}

// Per-batch min/max of el, er -> (mn, 30/(mx-mn)); leaky is monotone.
__global__ __launch_bounds__(256) void minmax_params(const float* __restrict__ el,
                                                     const float* __restrict__ er,
                                                     float2* __restrict__ params) {
  __shared__ float smnl[256], smxl[256], smnr[256], smxr[256];
  const int b = blockIdx.x, t = threadIdx.x;
  float mnl = 3.4e38f, mxl = -3.4e38f, mnr = 3.4e38f, mxr = -3.4e38f;
  for (int i = t; i < NN; i += 256) {
    float v = el[b * NN + i];
    mnl = fminf(mnl, v); mxl = fmaxf(mxl, v);
    float u = er[b * NN + i];
    mnr = fminf(mnr, u); mxr = fmaxf(mxr, u);
  }
  smnl[t] = mnl; smxl[t] = mxl; smnr[t] = mnr; smxr[t] = mxr;
  __syncthreads();
  for (int s = 128; s > 0; s >>= 1) {
    if (t < s) {
      smnl[t] = fminf(smnl[t], smnl[t + s]);
      smxl[t] = fmaxf(smxl[t], smxl[t + s]);
      smnr[t] = fminf(smnr[t], smnr[t + s]);
      smxr[t] = fmaxf(smxr[t], smxr[t + s]);
    }
    __syncthreads();
  }
  if (t == 0) {
    float mn = leakyf(smnl[0] + smnr[0]);
    float mx = leakyf(smxl[0] + smxr[0]);
    params[b] = make_float2(mn, 30.0f / (mx - mn));
  }
}

// ---------------------------------------------------------------------------
// Attention MFMA GEMM: C[i,f] = sum_j att(i,j)*h[j,f]. att synthesized fp32,
// RNE bf16 hi-only A-operand; h split B-operand (2 MFMA). Block 64 x 128.
// doElu: stage-1 epilogue. wg!=null: fuse wv[row] = sum_f C[row,f]*wg[f]
// (atomicAdd; requires gridDim.y == 1). B-operand register-prefetched.
// ---------------------------------------------------------------------------
__global__ __launch_bounds__(256) void gemm_att2(const float* __restrict__ el,
                                                 const float* __restrict__ er,
                                                 const float2* __restrict__ params,
                                                 const ushort_t* __restrict__ hThi,
                                                 const ushort_t* __restrict__ hTlo,
                                                 float* __restrict__ C,
                                                 const float* __restrict__ wg,
                                                 float* __restrict__ wv,
                                                 int Nc, int doElu) {
  __shared__ ushort_t Ah[64 * 40];
  __shared__ ushort_t Bh[128 * 40], Bl[128 * 40];
  __shared__ float ers[NN];
  __shared__ float wls[128];
  const int b = blockIdx.z, t = threadIdx.x, lane = t & 63, wid = t >> 6;
  const int wm = (wid & 1) * 32, wn = (wid >> 1) * 64;
  const int ln = lane & 15, quad = lane >> 4;
  const int m0 = blockIdx.x * 64, n0 = blockIdx.y * 128;
  const float2 p = params[b];
  const float npinv = -p.y;                  // q = exp(-e_s)
  const float npc   = p.x * p.y + 20.0f;
  *(float4*)&ers[t * 4] = *(const float4*)&er[b * NN + t * 4];
  if (wg && t < 128) wls[t] = wg[t];
  const int ra = t >> 2, ka = (t & 3) * 8;
  const float elv = el[b * NN + m0 + ra];
  const int rb = t >> 1, kb = (t & 1) * 16;
  const ushort_t* bph = hThi + (size_t)(n0 + rb) * MTOT + b * NN + kb;
  const ushort_t* bpl = hTlo + (size_t)(n0 + rb) * MTOT + b * NN + kb;
  f32x4 acc[2][4];
#pragma unroll
  for (int mi = 0; mi < 2; ++mi)
#pragma unroll
    for (int ni = 0; ni < 4; ++ni) acc[mi][ni] = (f32x4){0.f, 0.f, 0.f, 0.f};

  // ---- prologue: prefetch B tile k0=0
  uint4 vbh0 = *(const uint4*)(bph);
  uint4 vbh1 = *(const uint4*)(bph + 8);
  uint4 vbl0 = *(const uint4*)(bpl);
  uint4 vbl1 = *(const uint4*)(bpl + 8);
  __syncthreads();   // ers/wls visible

  for (int k0 = 0; k0 < NN; k0 += 32) {
    float s[8];
#pragma unroll
    for (int j = 0; j < 8; ++j) {
      float x = elv + ers[k0 + ka + j];
      x = fmaxf(x, 0.01f * x);
      s[j] = __builtin_amdgcn_rcpf(1.0f + __expf(fmaf(x, npinv, npc)));
    }
    uint4 av;
    av.x = pack_rne(s[0], s[1]); av.y = pack_rne(s[2], s[3]);
    av.z = pack_rne(s[4], s[5]); av.w = pack_rne(s[6], s[7]);
    __syncthreads();
    *(uint4*)&Ah[ra * 40 + ka] = av;
    *(uint4*)&Bh[rb * 40 + kb] = vbh0; *(uint4*)&Bh[rb * 40 + kb + 8] = vbh1;
    *(uint4*)&Bl[rb * 40 + kb] = vbl0; *(uint4*)&Bl[rb * 40 + kb + 8] = vbl1;
    __syncthreads();
    // ---- issue NEXT tile's B loads (clamped, branchless) before ds_read+MFMA
    const int kn = (k0 + 32 < NN) ? (k0 + 32) : 0;
    vbh0 = *(const uint4*)(bph + kn);
    vbh1 = *(const uint4*)(bph + kn + 8);
    vbl0 = *(const uint4*)(bpl + kn);
    vbl1 = *(const uint4*)(bpl + kn + 8);
    bf16x8 af[2], bhf[4], blf[4];
#pragma unroll
    for (int i = 0; i < 2; ++i) af[i] = *(const bf16x8*)&Ah[(wm + i * 16 + ln) * 40 + quad * 8];
#pragma unroll
    for (int i = 0; i < 4; ++i) {
      const int bo = (wn + i * 16 + ln) * 40 + quad * 8;
      bhf[i] = *(const bf16x8*)&Bh[bo];
      blf[i] = *(const bf16x8*)&Bl[bo];
    }
#pragma unroll
    for (int mi = 0; mi < 2; ++mi)
#pragma unroll
      for (int ni = 0; ni < 4; ++ni) {
        acc[mi][ni] = __builtin_amdgcn_mfma_f32_16x16x32_bf16(af[mi], bhf[ni], acc[mi][ni], 0, 0, 0);
        acc[mi][ni] = __builtin_amdgcn_mfma_f32_16x16x32_bf16(af[mi], blf[ni], acc[mi][ni], 0, 0, 0);
      }
  }
#pragma unroll
  for (int mi = 0; mi < 2; ++mi) {
    const int mrl = m0 + wm + mi * 16 + quad * 4;         // row within batch
    const size_t mrow = (size_t)b * NN + mrl;
#pragma unroll
    for (int ni = 0; ni < 4; ++ni) {
      const int c = n0 + wn + ni * 16 + ln;
#pragma unroll
      for (int rr = 0; rr < 4; ++rr) {
        float v = acc[mi][ni][rr];
        if (doElu) v = eluf(v);
        C[(mrow + rr) * Nc + c] = v;
      }
    }
    if (wg) {
#pragma unroll
      for (int rr = 0; rr < 4; ++rr) {
        float vw = 0.f;
#pragma unroll
        for (int ni = 0; ni < 4; ++ni)
          vw = fmaf(acc[mi][ni][rr], wls[wn + ni * 16 + ln], vw);
#pragma unroll
        for (int m = 1; m < 16; m <<= 1) vw += __shfl_xor(vw, m);
        if (ln == 0) atomicAdd(&wv[b * NN + mrl + rr], vw);
      }
    }
  }
}

// ---------------------------------------------------------------------------
// Fused: fc2[b,i,j] = att2(i,j) (fp32) AND out[b,i] = leaky(sum_j att*w + bg).
// One wave per row i; lanes cover 4 consecutive j each (coalesced float4).
// ---------------------------------------------------------------------------
__global__ __launch_bounds__(256) void final_out_fc2(const float* __restrict__ el,
                                                     const float* __restrict__ er,
                                                     const float2* __restrict__ params,
                                                     const float* __restrict__ w,
                                                     const float* __restrict__ bg,
                                                     float* __restrict__ fc2,
                                                     float* __restrict__ out) {
  const int row  = (blockIdx.x * 256 + threadIdx.x) >> 6;  // b*N+i
  const int lane = threadIdx.x & 63;
  const int b = row >> 10;
  const float2 p = params[b];
  const float npinv = -p.y;
  const float npc   = p.x * p.y + 20.0f;
  const float eli = el[row];
  const float* erb = er + (b << 10);
  const float* wb  = w + (b << 10);
  float* fcrow = fc2 + (size_t)row * NN;
  float s = 0.f;
  for (int j = lane * 4; j < NN; j += 256) {
    float4 e4 = *(const float4*)&erb[j];
    float4 w4 = *(const float4*)&wb[j];
    float4 a;
    a.x = __builtin_amdgcn_rcpf(1.0f + __expf(fmaf(leakyf(eli + e4.x), npinv, npc)));
    a.y = __builtin_amdgcn_rcpf(1.0f + __expf(fmaf(leakyf(eli + e4.y), npinv, npc)));
    a.z = __builtin_amdgcn_rcpf(1.0f + __expf(fmaf(leakyf(eli + e4.z), npinv, npc)));
    a.w = __builtin_amdgcn_rcpf(1.0f + __expf(fmaf(leakyf(eli + e4.w), npinv, npc)));
    s += w4.x * a.x + w4.y * a.y + w4.z * a.z + w4.w * a.w;
    *(float4*)&fcrow[j] = a;
  }
#pragma unroll
  for (int off = 32; off > 0; off >>= 1) s += __shfl_down(s, off);
  if (lane == 0) out[row] = leakyf(s + bg[0]);
}

extern "C" void kernel_launch(void* const* d_in, const int* in_sizes, int n_in,
                              void* d_out, int out_size, void* d_ws, size_t ws_size,
                              hipStream_t stream) {
  (void)in_sizes; (void)n_in; (void)out_size; (void)ws_size;
  const float* x  = (const float*)d_in[0];
  const float* W1 = (const float*)d_in[2];
  const float* a1 = (const float*)d_in[3];
  const float* W2 = (const float*)d_in[4];
  const float* a2 = (const float*)d_in[5];
  const float* Wg = (const float*)d_in[6];
  const float* bg = (const float*)d_in[7];

  float* out = (float*)d_out;               // [B,N,1]   32768
  float* fc2 = out + 32768;                 // [B,N,N]   33554432
  float* g2  = fc2 + 33554432;              // [B,N,H2]  4194304

  // Scratch inside the fc2 region (fc2 is written LAST, by final_out_fc2).
  ushort_t* h1Thi = (ushort_t*)fc2;                     // [256][32768]
  ushort_t* h1Tlo = (ushort_t*)(fc2 + 4194304);
  float*    g1    = fc2 + 8388608;                      // [32768][256] fp32
  ushort_t* h2Thi = (ushort_t*)(fc2 + 16777216);        // [128][32768]
  ushort_t* h2Tlo = (ushort_t*)(fc2 + 18874368);

  float* wsf = (float*)d_ws;
  float* el1 = wsf;                          // 32768 each; el1,er1,el2,er2,wv
  float* er1 = wsf + 32768;                  //   contiguous -> single memset
  float* el2 = wsf + 65536;
  float* er2 = wsf + 98304;
  float* wv  = wsf + 131072;
  float2* p1 = (float2*)(wsf + 163840);      // 32 float2
  float2* p2 = (float2*)(wsf + 163904);
  ushort_t* W1Thi = (ushort_t*)(wsf + 163968);   // [256][512]
  ushort_t* W1Tlo = (ushort_t*)(wsf + 229504);
  ushort_t* W2Thi = (ushort_t*)(wsf + 295040);   // [128][256]
  ushort_t* W2Tlo = (ushort_t*)(wsf + 311424);

  dim3 blk(256);
  hipMemsetAsync(wsf, 0, 5u * 32768u * sizeof(float), stream);   // el/er/wv = 0
  transpose_w_split<<<512, blk, 0, stream>>>(W1, W1Thi, W1Tlo, HH1, 9);
  transpose_w_split<<<128, blk, 0, stream>>>(W2, W2Thi, W2Tlo, HH2, 8);
  // Stage 1
  gemm_asplit<HH1><<<512, blk, 0, stream>>>(x, W1Thi, W1Tlo, a1,
                                            h1Thi, h1Tlo, el1, er1, FIN);
  minmax_params<<<32, blk, 0, stream>>>(el1, er1, p1);
  gemm_att2<<<dim3(16, 2, 32), blk, 0, stream>>>(el1, er1, p1, h1Thi, h1Tlo,
                                                 g1, nullptr, nullptr, HH1, 1);
  // Stage 2
  gemm_asplit<HH2><<<512, blk, 0, stream>>>(g1, W2Thi, W2Tlo, a2,
                                            h2Thi, h2Tlo, el2, er2, HH1);
  minmax_params<<<32, blk, 0, stream>>>(el2, er2, p2);
  gemm_att2<<<dim3(16, 1, 32), blk, 0, stream>>>(el2, er2, p2, h2Thi, h2Tlo,
                                                 g2, Wg, wv, HH2, 0);
  // Stage 3: fc2 + out (att recomputed on the fly; wv = g2 @ Wg already fused)
  final_out_fc2<<<8192, blk, 0, stream>>>(el2, er2, p2, wv, bg, fc2, out);
}

// Round 2
// 501.052 us; speedup vs baseline: 1.0356x; 1.0356x over previous
//
#include <hip/hip_runtime.h>

#define NN 1024
#define FIN 512
#define HH1 256
#define HH2 128
#define MTOT 32768   // B*N total rows

typedef unsigned short ushort_t;
using bf16x8 = __attribute__((ext_vector_type(8))) short;
using f32x4  = __attribute__((ext_vector_type(4))) float;

__device__ __forceinline__ float leakyf(float x) { return fmaxf(x, 0.01f * x); }
__device__ __forceinline__ float eluf(float x) { return x > 0.0f ? x : __expf(x) - 1.0f; }
// pack the high halves of two fp32 bit patterns: [u1.hi : u0.hi]
__device__ __forceinline__ unsigned pack_hi(unsigned u0, unsigned u1) {
  return __builtin_amdgcn_perm(u1, u0, 0x07060302u);
}
// trunc-split two fp32 -> bf16 hi pair + bf16 lo pair (lo compensates hi trunc)
__device__ __forceinline__ void split_pack2(float f0, float f1, unsigned& hp, unsigned& lp) {
  unsigned u0 = __float_as_uint(f0), u1 = __float_as_uint(f1);
  hp = pack_hi(u0, u1);
  float l0 = f0 - __uint_as_float(u0 & 0xFFFF0000u);
  float l1 = f1 - __uint_as_float(u1 & 0xFFFF0000u);
  lp = pack_hi(__float_as_uint(l0), __float_as_uint(l1));
}
// RNE-round two fp32 to bf16 and pack
__device__ __forceinline__ unsigned pack_rne(float f0, float f1) {
  unsigned u0 = __float_as_uint(f0); u0 += 0x7FFFu + ((u0 >> 16) & 1u);
  unsigned u1 = __float_as_uint(f1); u1 += 0x7FFFu + ((u1 >> 16) & 1u);
  return pack_hi(u0, u1);
}

// ---------------------------------------------------------------------------
// W[K][N] fp32 -> WT[N][K] trunc-split bf16. K = 1<<kshift.
// ---------------------------------------------------------------------------
__global__ __launch_bounds__(256) void transpose_w_split(const float* __restrict__ W,
                                                         ushort_t* __restrict__ WThi,
                                                         ushort_t* __restrict__ WTlo,
                                                         int Nc, int kshift) {
  int idx = blockIdx.x * 256 + threadIdx.x;
  int k = idx & ((1 << kshift) - 1);
  int n = idx >> kshift;
  float f = W[(size_t)k * Nc + n];
  unsigned u = __float_as_uint(f);
  WThi[idx] = (ushort_t)(u >> 16);
  float lo = f - __uint_as_float(u & 0xFFFF0000u);
  WTlo[idx] = (ushort_t)(__float_as_uint(lo) >> 16);
}

// ---------------------------------------------------------------------------
// Producer GEMM, full split precision (3 MFMA): C = A(fp32)[M,K] @ B, with
// B transposed split BT[NC][K]. In-kernel trunc-split of A. Block tile
// 64 x NC (y=1: each block sees full output rows). Outputs:
//   CT split [NC][MTOT]  (B-operand for the attention GEMM)
//   el/er row dots vs avec[0:NC]/avec[NC:2NC] from the fp32 accumulators,
//   reduced in-wave and atomicAdd'ed (el/er pre-zeroed).
// Epilogue: CT tile is staged through LDS (reusing the B buffers) and
// written with single-instruction FULL-LINE stores (4 lanes x 16B contiguous
// per column => whole 64B lines), eliminating the 5.7x partial-line HBM
// write amplification the old 64KB-strided uint2 scatter produced.
// ---------------------------------------------------------------------------
template<int NC>
__global__ __launch_bounds__(256) void gemm_asplit(const float* __restrict__ A,
                                                   const ushort_t* __restrict__ BThi,
                                                   const ushort_t* __restrict__ BTlo,
                                                   const float* __restrict__ avec,
                                                   ushort_t* __restrict__ CThi,
                                                   ushort_t* __restrict__ CTlo,
                                                   float* __restrict__ el,
                                                   float* __restrict__ er, int K) {
  constexpr int NFR = NC / 32;   // n-frags per wave (wave tile 32 x NC/2)
  constexpr int NB  = NC / 64;   // 16B B-chunks per thread per buffer
  __shared__ ushort_t Ah[64 * 40], Al[64 * 40];
  __shared__ ushort_t Bbuf[NC * 80];       // Bh | Bl during loop; stg after
  __shared__ float aL[NC], aR[NC];
  ushort_t* Bh = Bbuf;
  ushort_t* Bl = Bbuf + NC * 40;
  const int t = threadIdx.x, lane = t & 63, wid = t >> 6;
  const int wm = (wid & 1) * 32, wn = (wid >> 1) * (NC / 2);
  const int ln = lane & 15, quad = lane >> 4;
  const int m0 = blockIdx.x * 64;
  if (t < NC) { aL[t] = avec[t]; aR[t] = avec[NC + t]; }
  const int ra = t >> 2, ka = (t & 3) * 8;
  const float* ap = A + (size_t)(m0 + ra) * K + ka;
  const int brow = (t >> 2);            // + i*64 per chunk
  const int bko  = (t & 3) * 8;
  f32x4 acc[2][NFR];
#pragma unroll
  for (int mi = 0; mi < 2; ++mi)
#pragma unroll
    for (int ni = 0; ni < NFR; ++ni) acc[mi][ni] = (f32x4){0.f, 0.f, 0.f, 0.f};

  for (int k0 = 0; k0 < K; k0 += 32) {
    float4 fa0 = *(const float4*)(ap + k0);
    float4 fa1 = *(const float4*)(ap + k0 + 4);
    uint4 vbh[NB], vbl[NB];
#pragma unroll
    for (int i = 0; i < NB; ++i) {
      size_t off = (size_t)(brow + i * 64) * K + k0 + bko;
      vbh[i] = *(const uint4*)&BThi[off];
      vbl[i] = *(const uint4*)&BTlo[off];
    }
    uint4 ah4, al4;
    split_pack2(fa0.x, fa0.y, ah4.x, al4.x);
    split_pack2(fa0.z, fa0.w, ah4.y, al4.y);
    split_pack2(fa1.x, fa1.y, ah4.z, al4.z);
    split_pack2(fa1.z, fa1.w, ah4.w, al4.w);
    __syncthreads();
    *(uint4*)&Ah[ra * 40 + ka] = ah4;
    *(uint4*)&Al[ra * 40 + ka] = al4;
#pragma unroll
    for (int i = 0; i < NB; ++i) {
      *(uint4*)&Bh[(brow + i * 64) * 40 + bko] = vbh[i];
      *(uint4*)&Bl[(brow + i * 64) * 40 + bko] = vbl[i];
    }
    __syncthreads();
    bf16x8 ahf[2], alf[2], bhf[NFR], blf[NFR];
#pragma unroll
    for (int i = 0; i < 2; ++i) {
      const int ao = (wm + i * 16 + ln) * 40 + quad * 8;
      ahf[i] = *(const bf16x8*)&Ah[ao];
      alf[i] = *(const bf16x8*)&Al[ao];
    }
#pragma unroll
    for (int i = 0; i < NFR; ++i) {
      const int bo = (wn + i * 16 + ln) * 40 + quad * 8;
      bhf[i] = *(const bf16x8*)&Bh[bo];
      blf[i] = *(const bf16x8*)&Bl[bo];
    }
#pragma unroll
    for (int mi = 0; mi < 2; ++mi)
#pragma unroll
      for (int ni = 0; ni < NFR; ++ni) {
        acc[mi][ni] = __builtin_amdgcn_mfma_f32_16x16x32_bf16(ahf[mi], bhf[ni], acc[mi][ni], 0, 0, 0);
        acc[mi][ni] = __builtin_amdgcn_mfma_f32_16x16x32_bf16(ahf[mi], blf[ni], acc[mi][ni], 0, 0, 0);
        acc[mi][ni] = __builtin_amdgcn_mfma_f32_16x16x32_bf16(alf[mi], bhf[ni], acc[mi][ni], 0, 0, 0);
      }
  }

  // ---- el/er row-dot reduction (fp32 accumulators, unchanged) ----
#pragma unroll
  for (int mi = 0; mi < 2; ++mi) {
    const int mr = m0 + wm + mi * 16 + quad * 4;
#pragma unroll
    for (int rr = 0; rr < 4; ++rr) {
      float vel = 0.f, ver = 0.f;
#pragma unroll
      for (int ni = 0; ni < NFR; ++ni) {
        const int c = wn + ni * 16 + ln;
        vel = fmaf(acc[mi][ni][rr], aL[c], vel);
        ver = fmaf(acc[mi][ni][rr], aR[c], ver);
      }
#pragma unroll
      for (int m = 1; m < 16; m <<= 1) {
        vel += __shfl_xor(vel, m);
        ver += __shfl_xor(ver, m);
      }
      if (ln == 0) {
        atomicAdd(&el[mr + rr], vel);
        atomicAdd(&er[mr + rr], ver);
      }
    }
  }

  // ---- staged coalesced CT write: hi pass then lo pass ----
  // stg layout: [NC cols][66 rows-padded] ushort, overlaid on Bbuf.
  const int colbase = wid * (NC / 4);
  const int g = lane >> 2, j = lane & 3;
#pragma unroll
  for (int pass = 0; pass < 2; ++pass) {
    __syncthreads();   // loop ds_reads (pass 0) / prev-pass stg reads (pass 1) done
#pragma unroll
    for (int mi = 0; mi < 2; ++mi) {
      const int rbase = wm + mi * 16 + quad * 4;
#pragma unroll
      for (int ni = 0; ni < NFR; ++ni) {
        const int c = wn + ni * 16 + ln;
        unsigned h01, l01, h23, l23;
        split_pack2(acc[mi][ni][0], acc[mi][ni][1], h01, l01);
        split_pack2(acc[mi][ni][2], acc[mi][ni][3], h23, l23);
        uint2 v = pass ? make_uint2(l01, l23) : make_uint2(h01, h23);
        *(uint2*)&Bbuf[c * 66 + rbase] = v;
      }
    }
    __syncthreads();
    ushort_t* dst = pass ? CTlo : CThi;
#pragma unroll
    for (int cc = 0; cc < NC / 64; ++cc) {
      const int col = colbase + cc * 16 + g;
#pragma unroll
      for (int half = 0; half < 2; ++half) {
        const int r = half * 32 + j * 8;
        *(uint4*)&dst[(size_t)col * MTOT + m0 + r] = *(const uint4*)&Bbuf[col * 66 + r];
      }
    }
  }
}

// Per-batch min/max of el, er -> (mn, 30/(mx-mn)); leaky is monotone.
__global__ __launch_bounds__(256) void minmax_params(const float* __restrict__ el,
                                                     const float* __restrict__ er,
                                                     float2* __restrict__ params) {
  __shared__ float smnl[256], smxl[256], smnr[256], smxr[256];
  const int b = blockIdx.x, t = threadIdx.x;
  float mnl = 3.4e38f, mxl = -3.4e38f, mnr = 3.4e38f, mxr = -3.4e38f;
  for (int i = t; i < NN; i += 256) {
    float v = el[b * NN + i];
    mnl = fminf(mnl, v); mxl = fmaxf(mxl, v);
    float u = er[b * NN + i];
    mnr = fminf(mnr, u); mxr = fmaxf(mxr, u);
  }
  smnl[t] = mnl; smxl[t] = mxl; smnr[t] = mnr; smxr[t] = mxr;
  __syncthreads();
  for (int s = 128; s > 0; s >>= 1) {
    if (t < s) {
      smnl[t] = fminf(smnl[t], smnl[t + s]);
      smxl[t] = fmaxf(smxl[t], smxl[t + s]);
      smnr[t] = fminf(smnr[t], smnr[t + s]);
      smxr[t] = fmaxf(smxr[t], smxr[t + s]);
    }
    __syncthreads();
  }
  if (t == 0) {
    float mn = leakyf(smnl[0] + smnr[0]);
    float mx = leakyf(smxl[0] + smxr[0]);
    params[b] = make_float2(mn, 30.0f / (mx - mn));
  }
}

// ---------------------------------------------------------------------------
// Attention MFMA GEMM: C[i,f] = sum_j att(i,j)*h[j,f]. att synthesized fp32,
// RNE bf16 hi-only A-operand; h split B-operand (2 MFMA). Block 64 x 128.
// doElu: stage-1 epilogue. wg!=null: fuse wv[row] = sum_f C[row,f]*wg[f]
// (atomicAdd; requires gridDim.y == 1).
// ---------------------------------------------------------------------------
__global__ __launch_bounds__(256) void gemm_att2(const float* __restrict__ el,
                                                 const float* __restrict__ er,
                                                 const float2* __restrict__ params,
                                                 const ushort_t* __restrict__ hThi,
                                                 const ushort_t* __restrict__ hTlo,
                                                 float* __restrict__ C,
                                                 const float* __restrict__ wg,
                                                 float* __restrict__ wv,
                                                 int Nc, int doElu) {
  __shared__ ushort_t Ah[64 * 40];
  __shared__ ushort_t Bh[128 * 40], Bl[128 * 40];
  __shared__ float ers[NN];
  __shared__ float wls[128];
  const int b = blockIdx.z, t = threadIdx.x, lane = t & 63, wid = t >> 6;
  const int wm = (wid & 1) * 32, wn = (wid >> 1) * 64;
  const int ln = lane & 15, quad = lane >> 4;
  const int m0 = blockIdx.x * 64, n0 = blockIdx.y * 128;
  const float2 p = params[b];
  const float npinv = -p.y;                  // q = exp(-e_s)
  const float npc   = p.x * p.y + 20.0f;
  *(float4*)&ers[t * 4] = *(const float4*)&er[b * NN + t * 4];
  if (wg && t < 128) wls[t] = wg[t];
  const int ra = t >> 2, ka = (t & 3) * 8;
  const float elv = el[b * NN + m0 + ra];
  const int rb = t >> 1, kb = (t & 1) * 16;
  const ushort_t* bph = hThi + (size_t)(n0 + rb) * MTOT + b * NN + kb;
  const ushort_t* bpl = hTlo + (size_t)(n0 + rb) * MTOT + b * NN + kb;
  f32x4 acc[2][4];
#pragma unroll
  for (int mi = 0; mi < 2; ++mi)
#pragma unroll
    for (int ni = 0; ni < 4; ++ni) acc[mi][ni] = (f32x4){0.f, 0.f, 0.f, 0.f};
  __syncthreads();   // ers/wls visible

  for (int k0 = 0; k0 < NN; k0 += 32) {
    uint4 vbh0 = *(const uint4*)(bph + k0);
    uint4 vbh1 = *(const uint4*)(bph + k0 + 8);
    uint4 vbl0 = *(const uint4*)(bpl + k0);
    uint4 vbl1 = *(const uint4*)(bpl + k0 + 8);
    float s[8];
#pragma unroll
    for (int j = 0; j < 8; ++j) {
      float x = elv + ers[k0 + ka + j];
      x = fmaxf(x, 0.01f * x);
      s[j] = __builtin_amdgcn_rcpf(1.0f + __expf(fmaf(x, npinv, npc)));
    }
    uint4 av;
    av.x = pack_rne(s[0], s[1]); av.y = pack_rne(s[2], s[3]);
    av.z = pack_rne(s[4], s[5]); av.w = pack_rne(s[6], s[7]);
    __syncthreads();
    *(uint4*)&Ah[ra * 40 + ka] = av;
    *(uint4*)&Bh[rb * 40 + kb] = vbh0; *(uint4*)&Bh[rb * 40 + kb + 8] = vbh1;
    *(uint4*)&Bl[rb * 40 + kb] = vbl0; *(uint4*)&Bl[rb * 40 + kb + 8] = vbl1;
    __syncthreads();
    bf16x8 af[2], bhf[4], blf[4];
#pragma unroll
    for (int i = 0; i < 2; ++i) af[i] = *(const bf16x8*)&Ah[(wm + i * 16 + ln) * 40 + quad * 8];
#pragma unroll
    for (int i = 0; i < 4; ++i) {
      const int bo = (wn + i * 16 + ln) * 40 + quad * 8;
      bhf[i] = *(const bf16x8*)&Bh[bo];
      blf[i] = *(const bf16x8*)&Bl[bo];
    }
#pragma unroll
    for (int mi = 0; mi < 2; ++mi)
#pragma unroll
      for (int ni = 0; ni < 4; ++ni) {
        acc[mi][ni] = __builtin_amdgcn_mfma_f32_16x16x32_bf16(af[mi], bhf[ni], acc[mi][ni], 0, 0, 0);
        acc[mi][ni] = __builtin_amdgcn_mfma_f32_16x16x32_bf16(af[mi], blf[ni], acc[mi][ni], 0, 0, 0);
      }
  }
#pragma unroll
  for (int mi = 0; mi < 2; ++mi) {
    const int mrl = m0 + wm + mi * 16 + quad * 4;         // row within batch
    const size_t mrow = (size_t)b * NN + mrl;
#pragma unroll
    for (int ni = 0; ni < 4; ++ni) {
      const int c = n0 + wn + ni * 16 + ln;
#pragma unroll
      for (int rr = 0; rr < 4; ++rr) {
        float v = acc[mi][ni][rr];
        if (doElu) v = eluf(v);
        C[(mrow + rr) * Nc + c] = v;
      }
    }
    if (wg) {
#pragma unroll
      for (int rr = 0; rr < 4; ++rr) {
        float vw = 0.f;
#pragma unroll
        for (int ni = 0; ni < 4; ++ni)
          vw = fmaf(acc[mi][ni][rr], wls[wn + ni * 16 + ln], vw);
#pragma unroll
        for (int m = 1; m < 16; m <<= 1) vw += __shfl_xor(vw, m);
        if (ln == 0) atomicAdd(&wv[b * NN + mrl + rr], vw);
      }
    }
  }
}

// ---------------------------------------------------------------------------
// Fused: fc2[b,i,j] = att2(i,j) (fp32) AND out[b,i] = leaky(sum_j att*w + bg).
// One wave per row i; lanes cover 4 consecutive j each (coalesced float4).
// ---------------------------------------------------------------------------
__global__ __launch_bounds__(256) void final_out_fc2(const float* __restrict__ el,
                                                     const float* __restrict__ er,
                                                     const float2* __restrict__ params,
                                                     const float* __restrict__ w,
                                                     const float* __restrict__ bg,
                                                     float* __restrict__ fc2,
                                                     float* __restrict__ out) {
  const int row  = (blockIdx.x * 256 + threadIdx.x) >> 6;  // b*N+i
  const int lane = threadIdx.x & 63;
  const int b = row >> 10;
  const float2 p = params[b];
  const float npinv = -p.y;
  const float npc   = p.x * p.y + 20.0f;
  const float eli = el[row];
  const float* erb = er + (b << 10);
  const float* wb  = w + (b << 10);
  float* fcrow = fc2 + (size_t)row * NN;
  float s = 0.f;
  for (int j = lane * 4; j < NN; j += 256) {
    float4 e4 = *(const float4*)&erb[j];
    float4 w4 = *(const float4*)&wb[j];
    float4 a;
    a.x = __builtin_amdgcn_rcpf(1.0f + __expf(fmaf(leakyf(eli + e4.x), npinv, npc)));
    a.y = __builtin_amdgcn_rcpf(1.0f + __expf(fmaf(leakyf(eli + e4.y), npinv, npc)));
    a.z = __builtin_amdgcn_rcpf(1.0f + __expf(fmaf(leakyf(eli + e4.z), npinv, npc)));
    a.w = __builtin_amdgcn_rcpf(1.0f + __expf(fmaf(leakyf(eli + e4.w), npinv, npc)));
    s += w4.x * a.x + w4.y * a.y + w4.z * a.z + w4.w * a.w;
    *(float4*)&fcrow[j] = a;
  }
#pragma unroll
  for (int off = 32; off > 0; off >>= 1) s += __shfl_down(s, off);
  if (lane == 0) out[row] = leakyf(s + bg[0]);
}

extern "C" void kernel_launch(void* const* d_in, const int* in_sizes, int n_in,
                              void* d_out, int out_size, void* d_ws, size_t ws_size,
                              hipStream_t stream) {
  (void)in_sizes; (void)n_in; (void)out_size; (void)ws_size;
  const float* x  = (const float*)d_in[0];
  const float* W1 = (const float*)d_in[2];
  const float* a1 = (const float*)d_in[3];
  const float* W2 = (const float*)d_in[4];
  const float* a2 = (const float*)d_in[5];
  const float* Wg = (const float*)d_in[6];
  const float* bg = (const float*)d_in[7];

  float* out = (float*)d_out;               // [B,N,1]   32768
  float* fc2 = out + 32768;                 // [B,N,N]   33554432
  float* g2  = fc2 + 33554432;              // [B,N,H2]  4194304

  // Scratch inside the fc2 region (fc2 is written LAST, by final_out_fc2).
  ushort_t* h1Thi = (ushort_t*)fc2;                     // [256][32768]
  ushort_t* h1Tlo = (ushort_t*)(fc2 + 4194304);
  float*    g1    = fc2 + 8388608;                      // [32768][256] fp32
  ushort_t* h2Thi = (ushort_t*)(fc2 + 16777216);        // [128][32768]
  ushort_t* h2Tlo = (ushort_t*)(fc2 + 18874368);

  float* wsf = (float*)d_ws;
  float* el1 = wsf;                          // 32768 each; el1,er1,el2,er2,wv
  float* er1 = wsf + 32768;                  //   contiguous -> single memset
  float* el2 = wsf + 65536;
  float* er2 = wsf + 98304;
  float* wv  = wsf + 131072;
  float2* p1 = (float2*)(wsf + 163840);      // 32 float2
  float2* p2 = (float2*)(wsf + 163904);
  ushort_t* W1Thi = (ushort_t*)(wsf + 163968);   // [256][512]
  ushort_t* W1Tlo = (ushort_t*)(wsf + 229504);
  ushort_t* W2Thi = (ushort_t*)(wsf + 295040);   // [128][256]
  ushort_t* W2Tlo = (ushort_t*)(wsf + 311424);

  dim3 blk(256);
  hipMemsetAsync(wsf, 0, 5u * 32768u * sizeof(float), stream);   // el/er/wv = 0
  transpose_w_split<<<512, blk, 0, stream>>>(W1, W1Thi, W1Tlo, HH1, 9);
  transpose_w_split<<<128, blk, 0, stream>>>(W2, W2Thi, W2Tlo, HH2, 8);
  // Stage 1
  gemm_asplit<HH1><<<512, blk, 0, stream>>>(x, W1Thi, W1Tlo, a1,
                                            h1Thi, h1Tlo, el1, er1, FIN);
  minmax_params<<<32, blk, 0, stream>>>(el1, er1, p1);
  gemm_att2<<<dim3(16, 2, 32), blk, 0, stream>>>(el1, er1, p1, h1Thi, h1Tlo,
                                                 g1, nullptr, nullptr, HH1, 1);
  // Stage 2
  gemm_asplit<HH2><<<512, blk, 0, stream>>>(g1, W2Thi, W2Tlo, a2,
                                            h2Thi, h2Tlo, el2, er2, HH1);
  minmax_params<<<32, blk, 0, stream>>>(el2, er2, p2);
  gemm_att2<<<dim3(16, 1, 32), blk, 0, stream>>>(el2, er2, p2, h2Thi, h2Tlo,
                                                 g2, Wg, wv, HH2, 0);
  // Stage 3: fc2 + out (att recomputed on the fly; wv = g2 @ Wg already fused)
  final_out_fc2<<<8192, blk, 0, stream>>>(el2, er2, p2, wv, bg, fc2, out);
}

// Round 3
// 498.843 us; speedup vs baseline: 1.0401x; 1.0044x over previous
//
#include <hip/hip_runtime.h>

#define NN 1024
#define FIN 512
#define HH1 256
#define HH2 128
#define MTOT 32768   // B*N total rows

typedef unsigned short ushort_t;
using bf16x8 = __attribute__((ext_vector_type(8))) short;
using f32x4  = __attribute__((ext_vector_type(4))) float;

__device__ __forceinline__ float leakyf(float x) { return fmaxf(x, 0.01f * x); }
__device__ __forceinline__ float eluf(float x) { return x > 0.0f ? x : __expf(x) - 1.0f; }
// pack the high halves of two fp32 bit patterns: [u1.hi : u0.hi]
__device__ __forceinline__ unsigned pack_hi(unsigned u0, unsigned u1) {
  return __builtin_amdgcn_perm(u1, u0, 0x07060302u);
}
// trunc-split two fp32 -> bf16 hi pair + bf16 lo pair (lo compensates hi trunc)
__device__ __forceinline__ void split_pack2(float f0, float f1, unsigned& hp, unsigned& lp) {
  unsigned u0 = __float_as_uint(f0), u1 = __float_as_uint(f1);
  hp = pack_hi(u0, u1);
  float l0 = f0 - __uint_as_float(u0 & 0xFFFF0000u);
  float l1 = f1 - __uint_as_float(u1 & 0xFFFF0000u);
  lp = pack_hi(__float_as_uint(l0), __float_as_uint(l1));
}
// RNE-round two fp32 to bf16 and pack
__device__ __forceinline__ unsigned pack_rne(float f0, float f1) {
  unsigned u0 = __float_as_uint(f0); u0 += 0x7FFFu + ((u0 >> 16) & 1u);
  unsigned u1 = __float_as_uint(f1); u1 += 0x7FFFu + ((u1 >> 16) & 1u);
  return pack_hi(u0, u1);
}

// ---------------------------------------------------------------------------
// W[K][N] fp32 -> WT[N][K] trunc-split bf16. K = 1<<kshift.
// ---------------------------------------------------------------------------
__global__ __launch_bounds__(256) void transpose_w_split(const float* __restrict__ W,
                                                         ushort_t* __restrict__ WThi,
                                                         ushort_t* __restrict__ WTlo,
                                                         int Nc, int kshift) {
  int idx = blockIdx.x * 256 + threadIdx.x;
  int k = idx & ((1 << kshift) - 1);
  int n = idx >> kshift;
  float f = W[(size_t)k * Nc + n];
  unsigned u = __float_as_uint(f);
  WThi[idx] = (ushort_t)(u >> 16);
  float lo = f - __uint_as_float(u & 0xFFFF0000u);
  WTlo[idx] = (ushort_t)(__float_as_uint(lo) >> 16);
}

// ---------------------------------------------------------------------------
// Producer GEMM, full split precision (3 MFMA): C = A(fp32)[M,K] @ B, with
// B transposed split BT[NC][K]. In-kernel trunc-split of A. Block tile
// 64 x NC (y=1: each block sees full output rows). Outputs:
//   CT split, TILE-BLOCKED layout: CT_t[tile=M/64][NC][64 rows], so each
//   block writes its whole 32KB hi + 32KB lo output CONTIGUOUSLY (the old
//   [NC][MTOT] column-major layout scattered isolated 64B lines at 64KB
//   stride -> ~5x HBM write amplification / DRAM-page thrash).
//   el/er row dots vs avec[0:NC]/avec[NC:2NC] from the fp32 accumulators,
//   reduced in-wave and atomicAdd'ed (el/er pre-zeroed).
// ---------------------------------------------------------------------------
template<int NC>
__global__ __launch_bounds__(256) void gemm_asplit(const float* __restrict__ A,
                                                   const ushort_t* __restrict__ BThi,
                                                   const ushort_t* __restrict__ BTlo,
                                                   const float* __restrict__ avec,
                                                   ushort_t* __restrict__ CThi,
                                                   ushort_t* __restrict__ CTlo,
                                                   float* __restrict__ el,
                                                   float* __restrict__ er, int K) {
  constexpr int NFR = NC / 32;   // n-frags per wave (wave tile 32 x NC/2)
  constexpr int NB  = NC / 64;   // 16B B-chunks per thread per buffer
  __shared__ ushort_t Ah[64 * 40], Al[64 * 40];
  __shared__ ushort_t Bbuf[NC * 80];       // Bh | Bl during loop; stg after
  __shared__ float aL[NC], aR[NC];
  ushort_t* Bh = Bbuf;
  ushort_t* Bl = Bbuf + NC * 40;
  const int t = threadIdx.x, lane = t & 63, wid = t >> 6;
  const int wm = (wid & 1) * 32, wn = (wid >> 1) * (NC / 2);
  const int ln = lane & 15, quad = lane >> 4;
  const int m0 = blockIdx.x * 64;
  if (t < NC) { aL[t] = avec[t]; aR[t] = avec[NC + t]; }
  const int ra = t >> 2, ka = (t & 3) * 8;
  const float* ap = A + (size_t)(m0 + ra) * K + ka;
  const int brow = (t >> 2);            // + i*64 per chunk
  const int bko  = (t & 3) * 8;
  f32x4 acc[2][NFR];
#pragma unroll
  for (int mi = 0; mi < 2; ++mi)
#pragma unroll
    for (int ni = 0; ni < NFR; ++ni) acc[mi][ni] = (f32x4){0.f, 0.f, 0.f, 0.f};

  for (int k0 = 0; k0 < K; k0 += 32) {
    float4 fa0 = *(const float4*)(ap + k0);
    float4 fa1 = *(const float4*)(ap + k0 + 4);
    uint4 vbh[NB], vbl[NB];
#pragma unroll
    for (int i = 0; i < NB; ++i) {
      size_t off = (size_t)(brow + i * 64) * K + k0 + bko;
      vbh[i] = *(const uint4*)&BThi[off];
      vbl[i] = *(const uint4*)&BTlo[off];
    }
    uint4 ah4, al4;
    split_pack2(fa0.x, fa0.y, ah4.x, al4.x);
    split_pack2(fa0.z, fa0.w, ah4.y, al4.y);
    split_pack2(fa1.x, fa1.y, ah4.z, al4.z);
    split_pack2(fa1.z, fa1.w, ah4.w, al4.w);
    __syncthreads();
    *(uint4*)&Ah[ra * 40 + ka] = ah4;
    *(uint4*)&Al[ra * 40 + ka] = al4;
#pragma unroll
    for (int i = 0; i < NB; ++i) {
      *(uint4*)&Bh[(brow + i * 64) * 40 + bko] = vbh[i];
      *(uint4*)&Bl[(brow + i * 64) * 40 + bko] = vbl[i];
    }
    __syncthreads();
    bf16x8 ahf[2], alf[2], bhf[NFR], blf[NFR];
#pragma unroll
    for (int i = 0; i < 2; ++i) {
      const int ao = (wm + i * 16 + ln) * 40 + quad * 8;
      ahf[i] = *(const bf16x8*)&Ah[ao];
      alf[i] = *(const bf16x8*)&Al[ao];
    }
#pragma unroll
    for (int i = 0; i < NFR; ++i) {
      const int bo = (wn + i * 16 + ln) * 40 + quad * 8;
      bhf[i] = *(const bf16x8*)&Bh[bo];
      blf[i] = *(const bf16x8*)&Bl[bo];
    }
#pragma unroll
    for (int mi = 0; mi < 2; ++mi)
#pragma unroll
      for (int ni = 0; ni < NFR; ++ni) {
        acc[mi][ni] = __builtin_amdgcn_mfma_f32_16x16x32_bf16(ahf[mi], bhf[ni], acc[mi][ni], 0, 0, 0);
        acc[mi][ni] = __builtin_amdgcn_mfma_f32_16x16x32_bf16(ahf[mi], blf[ni], acc[mi][ni], 0, 0, 0);
        acc[mi][ni] = __builtin_amdgcn_mfma_f32_16x16x32_bf16(alf[mi], bhf[ni], acc[mi][ni], 0, 0, 0);
      }
  }

  // ---- el/er row-dot reduction (fp32 accumulators, unchanged) ----
#pragma unroll
  for (int mi = 0; mi < 2; ++mi) {
    const int mr = m0 + wm + mi * 16 + quad * 4;
#pragma unroll
    for (int rr = 0; rr < 4; ++rr) {
      float vel = 0.f, ver = 0.f;
#pragma unroll
      for (int ni = 0; ni < NFR; ++ni) {
        const int c = wn + ni * 16 + ln;
        vel = fmaf(acc[mi][ni][rr], aL[c], vel);
        ver = fmaf(acc[mi][ni][rr], aR[c], ver);
      }
#pragma unroll
      for (int m = 1; m < 16; m <<= 1) {
        vel += __shfl_xor(vel, m);
        ver += __shfl_xor(ver, m);
      }
      if (ln == 0) {
        atomicAdd(&el[mr + rr], vel);
        atomicAdd(&er[mr + rr], ver);
      }
    }
  }

  // ---- staged CT write, tile-blocked: fully contiguous 32KB per pass ----
  // stg layout: [NC cols][66 rows-padded] ushort, overlaid on Bbuf.
  ushort_t* dsthi = CThi + (size_t)blockIdx.x * (NC * 64);
  ushort_t* dstlo = CTlo + (size_t)blockIdx.x * (NC * 64);
  const int colbase = wid * (NC / 4);
  const int g = lane >> 2, j = lane & 3;
#pragma unroll
  for (int pass = 0; pass < 2; ++pass) {
    __syncthreads();   // loop ds_reads (pass 0) / prev-pass stg reads (pass 1) done
#pragma unroll
    for (int mi = 0; mi < 2; ++mi) {
      const int rbase = wm + mi * 16 + quad * 4;
#pragma unroll
      for (int ni = 0; ni < NFR; ++ni) {
        const int c = wn + ni * 16 + ln;
        unsigned h01, l01, h23, l23;
        split_pack2(acc[mi][ni][0], acc[mi][ni][1], h01, l01);
        split_pack2(acc[mi][ni][2], acc[mi][ni][3], h23, l23);
        uint2 v = pass ? make_uint2(l01, l23) : make_uint2(h01, h23);
        *(uint2*)&Bbuf[c * 66 + rbase] = v;
      }
    }
    __syncthreads();
    ushort_t* dst = pass ? dstlo : dsthi;
#pragma unroll
    for (int cc = 0; cc < NC / 64; ++cc) {
      const int col = colbase + cc * 16 + g;
#pragma unroll
      for (int half = 0; half < 2; ++half) {
        const int r = half * 32 + j * 8;
        *(uint4*)&dst[col * 64 + r] = *(const uint4*)&Bbuf[col * 66 + r];
      }
    }
  }
}

// Per-batch min/max of el, er -> (mn, 30/(mx-mn)); leaky is monotone.
__global__ __launch_bounds__(256) void minmax_params(const float* __restrict__ el,
                                                     const float* __restrict__ er,
                                                     float2* __restrict__ params) {
  __shared__ float smnl[256], smxl[256], smnr[256], smxr[256];
  const int b = blockIdx.x, t = threadIdx.x;
  float mnl = 3.4e38f, mxl = -3.4e38f, mnr = 3.4e38f, mxr = -3.4e38f;
  for (int i = t; i < NN; i += 256) {
    float v = el[b * NN + i];
    mnl = fminf(mnl, v); mxl = fmaxf(mxl, v);
    float u = er[b * NN + i];
    mnr = fminf(mnr, u); mxr = fmaxf(mxr, u);
  }
  smnl[t] = mnl; smxl[t] = mxl; smnr[t] = mnr; smxr[t] = mxr;
  __syncthreads();
  for (int s = 128; s > 0; s >>= 1) {
    if (t < s) {
      smnl[t] = fminf(smnl[t], smnl[t + s]);
      smxl[t] = fmaxf(smxl[t], smxl[t + s]);
      smnr[t] = fminf(smnr[t], smnr[t + s]);
      smxr[t] = fmaxf(smxr[t], smxr[t + s]);
    }
    __syncthreads();
  }
  if (t == 0) {
    float mn = leakyf(smnl[0] + smnr[0]);
    float mx = leakyf(smxl[0] + smxr[0]);
    params[b] = make_float2(mn, 30.0f / (mx - mn));
  }
}

// ---------------------------------------------------------------------------
// Attention MFMA GEMM: C[i,f] = sum_j att(i,j)*h[j,f]. att synthesized fp32,
// RNE bf16 hi-only A-operand; h split B-operand (2 MFMA). Block 64 x 128.
// h is in TILE-BLOCKED layout CT_t[tile][Nc][64]: per k-step the block reads
// 64B fully-used contiguous chunks walking sequentially through 32KB tiles.
// doElu: stage-1 epilogue. wg!=null: fuse wv[row] = sum_f C[row,f]*wg[f]
// (atomicAdd; requires gridDim.y == 1).
// ---------------------------------------------------------------------------
__global__ __launch_bounds__(256) void gemm_att2(const float* __restrict__ el,
                                                 const float* __restrict__ er,
                                                 const float2* __restrict__ params,
                                                 const ushort_t* __restrict__ hThi,
                                                 const ushort_t* __restrict__ hTlo,
                                                 float* __restrict__ C,
                                                 const float* __restrict__ wg,
                                                 float* __restrict__ wv,
                                                 int Nc, int doElu) {
  __shared__ ushort_t Ah[64 * 40];
  __shared__ ushort_t Bh[128 * 40], Bl[128 * 40];
  __shared__ float ers[NN];
  __shared__ float wls[128];
  const int b = blockIdx.z, t = threadIdx.x, lane = t & 63, wid = t >> 6;
  const int wm = (wid & 1) * 32, wn = (wid >> 1) * 64;
  const int ln = lane & 15, quad = lane >> 4;
  const int m0 = blockIdx.x * 64, n0 = blockIdx.y * 128;
  const float2 p = params[b];
  const float npinv = -p.y;                  // q = exp(-e_s)
  const float npc   = p.x * p.y + 20.0f;
  *(float4*)&ers[t * 4] = *(const float4*)&er[b * NN + t * 4];
  if (wg && t < 128) wls[t] = wg[t];
  const int ra = t >> 2, ka = (t & 3) * 8;
  const float elv = el[b * NN + m0 + ra];
  const int rb = t >> 1, kb = (t & 1) * 16;
  const size_t tstride = (size_t)Nc * 64;                 // ushorts per tile
  const size_t rowoff  = (size_t)(n0 + rb) * 64 + kb;     // within tile
  f32x4 acc[2][4];
#pragma unroll
  for (int mi = 0; mi < 2; ++mi)
#pragma unroll
    for (int ni = 0; ni < 4; ++ni) acc[mi][ni] = (f32x4){0.f, 0.f, 0.f, 0.f};
  __syncthreads();   // ers/wls visible

  for (int k0 = 0; k0 < NN; k0 += 32) {
    const size_t toff = (size_t)(b * 16 + (k0 >> 6)) * tstride + (size_t)(k0 & 32) + rowoff;
    uint4 vbh0 = *(const uint4*)&hThi[toff];
    uint4 vbh1 = *(const uint4*)&hThi[toff + 8];
    uint4 vbl0 = *(const uint4*)&hTlo[toff];
    uint4 vbl1 = *(const uint4*)&hTlo[toff + 8];
    float s[8];
#pragma unroll
    for (int j = 0; j < 8; ++j) {
      float x = elv + ers[k0 + ka + j];
      x = fmaxf(x, 0.01f * x);
      s[j] = __builtin_amdgcn_rcpf(1.0f + __expf(fmaf(x, npinv, npc)));
    }
    uint4 av;
    av.x = pack_rne(s[0], s[1]); av.y = pack_rne(s[2], s[3]);
    av.z = pack_rne(s[4], s[5]); av.w = pack_rne(s[6], s[7]);
    __syncthreads();
    *(uint4*)&Ah[ra * 40 + ka] = av;
    *(uint4*)&Bh[rb * 40 + kb] = vbh0; *(uint4*)&Bh[rb * 40 + kb + 8] = vbh1;
    *(uint4*)&Bl[rb * 40 + kb] = vbl0; *(uint4*)&Bl[rb * 40 + kb + 8] = vbl1;
    __syncthreads();
    bf16x8 af[2], bhf[4], blf[4];
#pragma unroll
    for (int i = 0; i < 2; ++i) af[i] = *(const bf16x8*)&Ah[(wm + i * 16 + ln) * 40 + quad * 8];
#pragma unroll
    for (int i = 0; i < 4; ++i) {
      const int bo = (wn + i * 16 + ln) * 40 + quad * 8;
      bhf[i] = *(const bf16x8*)&Bh[bo];
      blf[i] = *(const bf16x8*)&Bl[bo];
    }
#pragma unroll
    for (int mi = 0; mi < 2; ++mi)
#pragma unroll
      for (int ni = 0; ni < 4; ++ni) {
        acc[mi][ni] = __builtin_amdgcn_mfma_f32_16x16x32_bf16(af[mi], bhf[ni], acc[mi][ni], 0, 0, 0);
        acc[mi][ni] = __builtin_amdgcn_mfma_f32_16x16x32_bf16(af[mi], blf[ni], acc[mi][ni], 0, 0, 0);
      }
  }
#pragma unroll
  for (int mi = 0; mi < 2; ++mi) {
    const int mrl = m0 + wm + mi * 16 + quad * 4;         // row within batch
    const size_t mrow = (size_t)b * NN + mrl;
#pragma unroll
    for (int ni = 0; ni < 4; ++ni) {
      const int c = n0 + wn + ni * 16 + ln;
#pragma unroll
      for (int rr = 0; rr < 4; ++rr) {
        float v = acc[mi][ni][rr];
        if (doElu) v = eluf(v);
        C[(mrow + rr) * Nc + c] = v;
      }
    }
    if (wg) {
#pragma unroll
      for (int rr = 0; rr < 4; ++rr) {
        float vw = 0.f;
#pragma unroll
        for (int ni = 0; ni < 4; ++ni)
          vw = fmaf(acc[mi][ni][rr], wls[wn + ni * 16 + ln], vw);
#pragma unroll
        for (int m = 1; m < 16; m <<= 1) vw += __shfl_xor(vw, m);
        if (ln == 0) atomicAdd(&wv[b * NN + mrl + rr], vw);
      }
    }
  }
}

// ---------------------------------------------------------------------------
// Fused: fc2[b,i,j] = att2(i,j) (fp32) AND out[b,i] = leaky(sum_j att*w + bg).
// One wave per row i; lanes cover 4 consecutive j each (coalesced float4).
// ---------------------------------------------------------------------------
__global__ __launch_bounds__(256) void final_out_fc2(const float* __restrict__ el,
                                                     const float* __restrict__ er,
                                                     const float2* __restrict__ params,
                                                     const float* __restrict__ w,
                                                     const float* __restrict__ bg,
                                                     float* __restrict__ fc2,
                                                     float* __restrict__ out) {
  const int row  = (blockIdx.x * 256 + threadIdx.x) >> 6;  // b*N+i
  const int lane = threadIdx.x & 63;
  const int b = row >> 10;
  const float2 p = params[b];
  const float npinv = -p.y;
  const float npc   = p.x * p.y + 20.0f;
  const float eli = el[row];
  const float* erb = er + (b << 10);
  const float* wb  = w + (b << 10);
  float* fcrow = fc2 + (size_t)row * NN;
  float s = 0.f;
  for (int j = lane * 4; j < NN; j += 256) {
    float4 e4 = *(const float4*)&erb[j];
    float4 w4 = *(const float4*)&wb[j];
    float4 a;
    a.x = __builtin_amdgcn_rcpf(1.0f + __expf(fmaf(leakyf(eli + e4.x), npinv, npc)));
    a.y = __builtin_amdgcn_rcpf(1.0f + __expf(fmaf(leakyf(eli + e4.y), npinv, npc)));
    a.z = __builtin_amdgcn_rcpf(1.0f + __expf(fmaf(leakyf(eli + e4.z), npinv, npc)));
    a.w = __builtin_amdgcn_rcpf(1.0f + __expf(fmaf(leakyf(eli + e4.w), npinv, npc)));
    s += w4.x * a.x + w4.y * a.y + w4.z * a.z + w4.w * a.w;
    *(float4*)&fcrow[j] = a;
  }
#pragma unroll
  for (int off = 32; off > 0; off >>= 1) s += __shfl_down(s, off);
  if (lane == 0) out[row] = leakyf(s + bg[0]);
}

extern "C" void kernel_launch(void* const* d_in, const int* in_sizes, int n_in,
                              void* d_out, int out_size, void* d_ws, size_t ws_size,
                              hipStream_t stream) {
  (void)in_sizes; (void)n_in; (void)out_size; (void)ws_size;
  const float* x  = (const float*)d_in[0];
  const float* W1 = (const float*)d_in[2];
  const float* a1 = (const float*)d_in[3];
  const float* W2 = (const float*)d_in[4];
  const float* a2 = (const float*)d_in[5];
  const float* Wg = (const float*)d_in[6];
  const float* bg = (const float*)d_in[7];

  float* out = (float*)d_out;               // [B,N,1]   32768
  float* fc2 = out + 32768;                 // [B,N,N]   33554432
  float* g2  = fc2 + 33554432;              // [B,N,H2]  4194304

  // Scratch inside the fc2 region (fc2 is written LAST, by final_out_fc2).
  ushort_t* h1Thi = (ushort_t*)fc2;                     // [512][256][64] tiled
  ushort_t* h1Tlo = (ushort_t*)(fc2 + 4194304);
  float*    g1    = fc2 + 8388608;                      // [32768][256] fp32
  ushort_t* h2Thi = (ushort_t*)(fc2 + 16777216);        // [512][128][64] tiled
  ushort_t* h2Tlo = (ushort_t*)(fc2 + 18874368);

  float* wsf = (float*)d_ws;
  float* el1 = wsf;                          // 32768 each; el1,er1,el2,er2,wv
  float* er1 = wsf + 32768;                  //   contiguous -> single memset
  float* el2 = wsf + 65536;
  float* er2 = wsf + 98304;
  float* wv  = wsf + 131072;
  float2* p1 = (float2*)(wsf + 163840);      // 32 float2
  float2* p2 = (float2*)(wsf + 163904);
  ushort_t* W1Thi = (ushort_t*)(wsf + 163968);   // [256][512]
  ushort_t* W1Tlo = (ushort_t*)(wsf + 229504);
  ushort_t* W2Thi = (ushort_t*)(wsf + 295040);   // [128][256]
  ushort_t* W2Tlo = (ushort_t*)(wsf + 311424);

  dim3 blk(256);
  hipMemsetAsync(wsf, 0, 5u * 32768u * sizeof(float), stream);   // el/er/wv = 0
  transpose_w_split<<<512, blk, 0, stream>>>(W1, W1Thi, W1Tlo, HH1, 9);
  transpose_w_split<<<128, blk, 0, stream>>>(W2, W2Thi, W2Tlo, HH2, 8);
  // Stage 1
  gemm_asplit<HH1><<<512, blk, 0, stream>>>(x, W1Thi, W1Tlo, a1,
                                            h1Thi, h1Tlo, el1, er1, FIN);
  minmax_params<<<32, blk, 0, stream>>>(el1, er1, p1);
  gemm_att2<<<dim3(16, 2, 32), blk, 0, stream>>>(el1, er1, p1, h1Thi, h1Tlo,
                                                 g1, nullptr, nullptr, HH1, 1);
  // Stage 2
  gemm_asplit<HH2><<<512, blk, 0, stream>>>(g1, W2Thi, W2Tlo, a2,
                                            h2Thi, h2Tlo, el2, er2, HH1);
  minmax_params<<<32, blk, 0, stream>>>(el2, er2, p2);
  gemm_att2<<<dim3(16, 1, 32), blk, 0, stream>>>(el2, er2, p2, h2Thi, h2Tlo,
                                                 g2, Wg, wv, HH2, 0);
  // Stage 3: fc2 + out (att recomputed on the fly; wv = g2 @ Wg already fused)
  final_out_fc2<<<8192, blk, 0, stream>>>(el2, er2, p2, wv, bg, fc2, out);
}

// Round 4
// 484.845 us; speedup vs baseline: 1.0702x; 1.0289x over previous
//
#include <hip/hip_runtime.h>

#define NN 1024
#define FIN 512
#define HH1 256
#define HH2 128
#define MTOT 32768   // B*N total rows

typedef unsigned short ushort_t;
using bf16x8 = __attribute__((ext_vector_type(8))) short;
using f32x4  = __attribute__((ext_vector_type(4))) float;

__device__ __forceinline__ float leakyf(float x) { return fmaxf(x, 0.01f * x); }
__device__ __forceinline__ float eluf(float x) { return x > 0.0f ? x : __expf(x) - 1.0f; }
// pack the high halves of two fp32 bit patterns: [u1.hi : u0.hi]
__device__ __forceinline__ unsigned pack_hi(unsigned u0, unsigned u1) {
  return __builtin_amdgcn_perm(u1, u0, 0x07060302u);
}
// trunc-split two fp32 -> bf16 hi pair + bf16 lo pair (lo compensates hi trunc)
__device__ __forceinline__ void split_pack2(float f0, float f1, unsigned& hp, unsigned& lp) {
  unsigned u0 = __float_as_uint(f0), u1 = __float_as_uint(f1);
  hp = pack_hi(u0, u1);
  float l0 = f0 - __uint_as_float(u0 & 0xFFFF0000u);
  float l1 = f1 - __uint_as_float(u1 & 0xFFFF0000u);
  lp = pack_hi(__float_as_uint(l0), __float_as_uint(l1));
}
// RNE-round two fp32 to bf16 and pack
__device__ __forceinline__ unsigned pack_rne(float f0, float f1) {
  unsigned u0 = __float_as_uint(f0); u0 += 0x7FFFu + ((u0 >> 16) & 1u);
  unsigned u1 = __float_as_uint(f1); u1 += 0x7FFFu + ((u1 >> 16) & 1u);
  return pack_hi(u0, u1);
}

// ---------------------------------------------------------------------------
// W[K][N] fp32 -> WT[N][K] trunc-split bf16. K = 1<<kshift.
// ---------------------------------------------------------------------------
__global__ __launch_bounds__(256) void transpose_w_split(const float* __restrict__ W,
                                                         ushort_t* __restrict__ WThi,
                                                         ushort_t* __restrict__ WTlo,
                                                         int Nc, int kshift) {
  int idx = blockIdx.x * 256 + threadIdx.x;
  int k = idx & ((1 << kshift) - 1);
  int n = idx >> kshift;
  float f = W[(size_t)k * Nc + n];
  unsigned u = __float_as_uint(f);
  WThi[idx] = (ushort_t)(u >> 16);
  float lo = f - __uint_as_float(u & 0xFFFF0000u);
  WTlo[idx] = (ushort_t)(__float_as_uint(lo) >> 16);
}

// ---------------------------------------------------------------------------
// Producer GEMM, full split precision (3 MFMA): C = A(fp32)[M,K] @ B, with
// B transposed split BT[NC][K]. Block tile 64 x NCB; gridDim.y = NC/NCB
// n-blocks per m-tile (occupancy: grid was 512 = 2 blocks/CU, all pipes <22%
// busy and latency-bound; n-split doubles resident blocks to 4/CU).
// Outputs:
//   CT split, TILE-BLOCKED layout CT_t[tile=M/64][NC][64 rows]; each block
//   writes its [NCB][64] slice contiguously.
//   el/er partial row dots vs avec slices, reduced in-wave and atomicAdd'ed
//   across n-blocks (el/er pre-zeroed).
// ---------------------------------------------------------------------------
template<int NC, int NCB>
__global__ __launch_bounds__(256, 4) void gemm_asplit(const float* __restrict__ A,
                                                      const ushort_t* __restrict__ BThi,
                                                      const ushort_t* __restrict__ BTlo,
                                                      const float* __restrict__ avec,
                                                      ushort_t* __restrict__ CThi,
                                                      ushort_t* __restrict__ CTlo,
                                                      float* __restrict__ el,
                                                      float* __restrict__ er, int K) {
  constexpr int NFR = NCB / 32;   // n-frags per wave (wave tile 32 x NCB/2)
  constexpr int NB  = NCB / 64;   // 16B B-chunks per thread per buffer
  __shared__ ushort_t Ah[64 * 40], Al[64 * 40];
  __shared__ ushort_t Bbuf[NCB * 80];      // Bh | Bl during loop; stg after
  __shared__ float aL[NCB], aR[NCB];
  ushort_t* Bh = Bbuf;
  ushort_t* Bl = Bbuf + NCB * 40;
  const int t = threadIdx.x, lane = t & 63, wid = t >> 6;
  const int wm = (wid & 1) * 32, wn = (wid >> 1) * (NCB / 2);
  const int ln = lane & 15, quad = lane >> 4;
  const int m0 = blockIdx.x * 64;
  const int n0c = blockIdx.y * NCB;
  if (t < NCB) { aL[t] = avec[n0c + t]; aR[t] = avec[NC + n0c + t]; }
  const int ra = t >> 2, ka = (t & 3) * 8;
  const float* ap = A + (size_t)(m0 + ra) * K + ka;
  const int brow = (t >> 2);            // + i*64 per chunk
  const int bko  = (t & 3) * 8;
  f32x4 acc[2][NFR];
#pragma unroll
  for (int mi = 0; mi < 2; ++mi)
#pragma unroll
    for (int ni = 0; ni < NFR; ++ni) acc[mi][ni] = (f32x4){0.f, 0.f, 0.f, 0.f};

  for (int k0 = 0; k0 < K; k0 += 32) {
    float4 fa0 = *(const float4*)(ap + k0);
    float4 fa1 = *(const float4*)(ap + k0 + 4);
    uint4 vbh[NB], vbl[NB];
#pragma unroll
    for (int i = 0; i < NB; ++i) {
      size_t off = (size_t)(n0c + brow + i * 64) * K + k0 + bko;
      vbh[i] = *(const uint4*)&BThi[off];
      vbl[i] = *(const uint4*)&BTlo[off];
    }
    uint4 ah4, al4;
    split_pack2(fa0.x, fa0.y, ah4.x, al4.x);
    split_pack2(fa0.z, fa0.w, ah4.y, al4.y);
    split_pack2(fa1.x, fa1.y, ah4.z, al4.z);
    split_pack2(fa1.z, fa1.w, ah4.w, al4.w);
    __syncthreads();
    *(uint4*)&Ah[ra * 40 + ka] = ah4;
    *(uint4*)&Al[ra * 40 + ka] = al4;
#pragma unroll
    for (int i = 0; i < NB; ++i) {
      *(uint4*)&Bh[(brow + i * 64) * 40 + bko] = vbh[i];
      *(uint4*)&Bl[(brow + i * 64) * 40 + bko] = vbl[i];
    }
    __syncthreads();
    bf16x8 ahf[2], alf[2], bhf[NFR], blf[NFR];
#pragma unroll
    for (int i = 0; i < 2; ++i) {
      const int ao = (wm + i * 16 + ln) * 40 + quad * 8;
      ahf[i] = *(const bf16x8*)&Ah[ao];
      alf[i] = *(const bf16x8*)&Al[ao];
    }
#pragma unroll
    for (int i = 0; i < NFR; ++i) {
      const int bo = (wn + i * 16 + ln) * 40 + quad * 8;
      bhf[i] = *(const bf16x8*)&Bh[bo];
      blf[i] = *(const bf16x8*)&Bl[bo];
    }
#pragma unroll
    for (int mi = 0; mi < 2; ++mi)
#pragma unroll
      for (int ni = 0; ni < NFR; ++ni) {
        acc[mi][ni] = __builtin_amdgcn_mfma_f32_16x16x32_bf16(ahf[mi], bhf[ni], acc[mi][ni], 0, 0, 0);
        acc[mi][ni] = __builtin_amdgcn_mfma_f32_16x16x32_bf16(ahf[mi], blf[ni], acc[mi][ni], 0, 0, 0);
        acc[mi][ni] = __builtin_amdgcn_mfma_f32_16x16x32_bf16(alf[mi], bhf[ni], acc[mi][ni], 0, 0, 0);
      }
  }

  // ---- el/er partial row-dot reduction over this block's NCB cols ----
#pragma unroll
  for (int mi = 0; mi < 2; ++mi) {
    const int mr = m0 + wm + mi * 16 + quad * 4;
#pragma unroll
    for (int rr = 0; rr < 4; ++rr) {
      float vel = 0.f, ver = 0.f;
#pragma unroll
      for (int ni = 0; ni < NFR; ++ni) {
        const int c = wn + ni * 16 + ln;
        vel = fmaf(acc[mi][ni][rr], aL[c], vel);
        ver = fmaf(acc[mi][ni][rr], aR[c], ver);
      }
#pragma unroll
      for (int m = 1; m < 16; m <<= 1) {
        vel += __shfl_xor(vel, m);
        ver += __shfl_xor(ver, m);
      }
      if (ln == 0) {
        atomicAdd(&el[mr + rr], vel);
        atomicAdd(&er[mr + rr], ver);
      }
    }
  }

  // ---- staged CT write, tile-blocked: contiguous [NCB][64] slice ----
  // stg layout: [NCB cols][66 rows-padded] ushort, overlaid on Bbuf.
  ushort_t* dsthi = CThi + (size_t)blockIdx.x * (NC * 64) + (size_t)n0c * 64;
  ushort_t* dstlo = CTlo + (size_t)blockIdx.x * (NC * 64) + (size_t)n0c * 64;
  const int colbase = wid * (NCB / 4);
  const int g = lane >> 2, j = lane & 3;
#pragma unroll
  for (int pass = 0; pass < 2; ++pass) {
    __syncthreads();   // loop ds_reads (pass 0) / prev-pass stg reads (pass 1) done
#pragma unroll
    for (int mi = 0; mi < 2; ++mi) {
      const int rbase = wm + mi * 16 + quad * 4;
#pragma unroll
      for (int ni = 0; ni < NFR; ++ni) {
        const int c = wn + ni * 16 + ln;
        unsigned h01, l01, h23, l23;
        split_pack2(acc[mi][ni][0], acc[mi][ni][1], h01, l01);
        split_pack2(acc[mi][ni][2], acc[mi][ni][3], h23, l23);
        uint2 v = pass ? make_uint2(l01, l23) : make_uint2(h01, h23);
        *(uint2*)&Bbuf[c * 66 + rbase] = v;
      }
    }
    __syncthreads();
    ushort_t* dst = pass ? dstlo : dsthi;
#pragma unroll
    for (int cc = 0; cc < NCB / 64; ++cc) {
      const int col = colbase + cc * 16 + g;
#pragma unroll
      for (int half = 0; half < 2; ++half) {
        const int r = half * 32 + j * 8;
        *(uint4*)&dst[col * 64 + r] = *(const uint4*)&Bbuf[col * 66 + r];
      }
    }
  }
}

// Per-batch min/max of el, er -> (mn, 30/(mx-mn)); leaky is monotone.
__global__ __launch_bounds__(256) void minmax_params(const float* __restrict__ el,
                                                     const float* __restrict__ er,
                                                     float2* __restrict__ params) {
  __shared__ float smnl[256], smxl[256], smnr[256], smxr[256];
  const int b = blockIdx.x, t = threadIdx.x;
  float mnl = 3.4e38f, mxl = -3.4e38f, mnr = 3.4e38f, mxr = -3.4e38f;
  for (int i = t; i < NN; i += 256) {
    float v = el[b * NN + i];
    mnl = fminf(mnl, v); mxl = fmaxf(mxl, v);
    float u = er[b * NN + i];
    mnr = fminf(mnr, u); mxr = fmaxf(mxr, u);
  }
  smnl[t] = mnl; smxl[t] = mxl; smnr[t] = mnr; smxr[t] = mxr;
  __syncthreads();
  for (int s = 128; s > 0; s >>= 1) {
    if (t < s) {
      smnl[t] = fminf(smnl[t], smnl[t + s]);
      smxl[t] = fmaxf(smxl[t], smxl[t + s]);
      smnr[t] = fminf(smnr[t], smnr[t + s]);
      smxr[t] = fmaxf(smxr[t], smxr[t + s]);
    }
    __syncthreads();
  }
  if (t == 0) {
    float mn = leakyf(smnl[0] + smnr[0]);
    float mx = leakyf(smxl[0] + smxr[0]);
    params[b] = make_float2(mn, 30.0f / (mx - mn));
  }
}

// ---------------------------------------------------------------------------
// Attention MFMA GEMM: C[i,f] = sum_j att(i,j)*h[j,f]. att synthesized fp32,
// RNE bf16 hi-only A-operand; h split B-operand (2 MFMA). Block 64 x BW,
// gridDim.y = Nc/BW. h is in TILE-BLOCKED layout CT_t[tile][Nc][64].
// doElu: stage-1 epilogue. wg!=null: fuse wv[row] += sum_{f in block} C*wg[f]
// (atomicAdd across y-blocks; wv pre-zeroed).
// ---------------------------------------------------------------------------
template<int BW>
__global__ __launch_bounds__(256, 4) void gemm_att2(const float* __restrict__ el,
                                                    const float* __restrict__ er,
                                                    const float2* __restrict__ params,
                                                    const ushort_t* __restrict__ hThi,
                                                    const ushort_t* __restrict__ hTlo,
                                                    float* __restrict__ C,
                                                    const float* __restrict__ wg,
                                                    float* __restrict__ wv,
                                                    int Nc, int doElu) {
  constexpr int NFR = BW / 32;
  __shared__ ushort_t Ah[64 * 40];
  __shared__ ushort_t Bh[BW * 40], Bl[BW * 40];
  __shared__ float ers[NN];
  __shared__ float wls[BW];
  const int b = blockIdx.z, t = threadIdx.x, lane = t & 63, wid = t >> 6;
  const int wm = (wid & 1) * 32, wn = (wid >> 1) * (BW / 2);
  const int ln = lane & 15, quad = lane >> 4;
  const int m0 = blockIdx.x * 64, n0 = blockIdx.y * BW;
  const float2 p = params[b];
  const float npinv = -p.y;                  // q = exp(-e_s)
  const float npc   = p.x * p.y + 20.0f;
  *(float4*)&ers[t * 4] = *(const float4*)&er[b * NN + t * 4];
  if (wg && t < BW) wls[t] = wg[n0 + t];
  const int ra = t >> 2, ka = (t & 3) * 8;
  const float elv = el[b * NN + m0 + ra];
  // B loader geometry: BW=128 -> 2 uint4/thread/buf; BW=64 -> 1 uint4.
  const int rb = (BW == 128) ? (t >> 1) : (t >> 2);
  const int kb = (BW == 128) ? ((t & 1) * 16) : ((t & 3) * 8);
  const size_t tstride = (size_t)Nc * 64;                 // ushorts per tile
  const size_t rowoff  = (size_t)(n0 + rb) * 64 + kb;     // within tile
  f32x4 acc[2][NFR];
#pragma unroll
  for (int mi = 0; mi < 2; ++mi)
#pragma unroll
    for (int ni = 0; ni < NFR; ++ni) acc[mi][ni] = (f32x4){0.f, 0.f, 0.f, 0.f};
  __syncthreads();   // ers/wls visible

  for (int k0 = 0; k0 < NN; k0 += 32) {
    const size_t toff = (size_t)(b * 16 + (k0 >> 6)) * tstride + (size_t)(k0 & 32) + rowoff;
    uint4 vbh0 = *(const uint4*)&hThi[toff];
    uint4 vbl0 = *(const uint4*)&hTlo[toff];
    uint4 vbh1, vbl1;
    if constexpr (BW == 128) {
      vbh1 = *(const uint4*)&hThi[toff + 8];
      vbl1 = *(const uint4*)&hTlo[toff + 8];
    }
    float s[8];
#pragma unroll
    for (int j = 0; j < 8; ++j) {
      float x = elv + ers[k0 + ka + j];
      x = fmaxf(x, 0.01f * x);
      s[j] = __builtin_amdgcn_rcpf(1.0f + __expf(fmaf(x, npinv, npc)));
    }
    uint4 av;
    av.x = pack_rne(s[0], s[1]); av.y = pack_rne(s[2], s[3]);
    av.z = pack_rne(s[4], s[5]); av.w = pack_rne(s[6], s[7]);
    __syncthreads();
    *(uint4*)&Ah[ra * 40 + ka] = av;
    *(uint4*)&Bh[rb * 40 + kb] = vbh0;
    *(uint4*)&Bl[rb * 40 + kb] = vbl0;
    if constexpr (BW == 128) {
      *(uint4*)&Bh[rb * 40 + kb + 8] = vbh1;
      *(uint4*)&Bl[rb * 40 + kb + 8] = vbl1;
    }
    __syncthreads();
    bf16x8 af[2], bhf[NFR], blf[NFR];
#pragma unroll
    for (int i = 0; i < 2; ++i) af[i] = *(const bf16x8*)&Ah[(wm + i * 16 + ln) * 40 + quad * 8];
#pragma unroll
    for (int i = 0; i < NFR; ++i) {
      const int bo = (wn + i * 16 + ln) * 40 + quad * 8;
      bhf[i] = *(const bf16x8*)&Bh[bo];
      blf[i] = *(const bf16x8*)&Bl[bo];
    }
#pragma unroll
    for (int mi = 0; mi < 2; ++mi)
#pragma unroll
      for (int ni = 0; ni < NFR; ++ni) {
        acc[mi][ni] = __builtin_amdgcn_mfma_f32_16x16x32_bf16(af[mi], bhf[ni], acc[mi][ni], 0, 0, 0);
        acc[mi][ni] = __builtin_amdgcn_mfma_f32_16x16x32_bf16(af[mi], blf[ni], acc[mi][ni], 0, 0, 0);
      }
  }
#pragma unroll
  for (int mi = 0; mi < 2; ++mi) {
    const int mrl = m0 + wm + mi * 16 + quad * 4;         // row within batch
    const size_t mrow = (size_t)b * NN + mrl;
#pragma unroll
    for (int ni = 0; ni < NFR; ++ni) {
      const int c = n0 + wn + ni * 16 + ln;
#pragma unroll
      for (int rr = 0; rr < 4; ++rr) {
        float v = acc[mi][ni][rr];
        if (doElu) v = eluf(v);
        C[(mrow + rr) * Nc + c] = v;
      }
    }
    if (wg) {
#pragma unroll
      for (int rr = 0; rr < 4; ++rr) {
        float vw = 0.f;
#pragma unroll
        for (int ni = 0; ni < NFR; ++ni)
          vw = fmaf(acc[mi][ni][rr], wls[wn + ni * 16 + ln], vw);
#pragma unroll
        for (int m = 1; m < 16; m <<= 1) vw += __shfl_xor(vw, m);
        if (ln == 0) atomicAdd(&wv[b * NN + mrl + rr], vw);
      }
    }
  }
}

// ---------------------------------------------------------------------------
// Fused: fc2[b,i,j] = att2(i,j) (fp32) AND out[b,i] = leaky(sum_j att*w + bg).
// One wave per row i; lanes cover 4 consecutive j each (coalesced float4).
// ---------------------------------------------------------------------------
__global__ __launch_bounds__(256) void final_out_fc2(const float* __restrict__ el,
                                                     const float* __restrict__ er,
                                                     const float2* __restrict__ params,
                                                     const float* __restrict__ w,
                                                     const float* __restrict__ bg,
                                                     float* __restrict__ fc2,
                                                     float* __restrict__ out) {
  const int row  = (blockIdx.x * 256 + threadIdx.x) >> 6;  // b*N+i
  const int lane = threadIdx.x & 63;
  const int b = row >> 10;
  const float2 p = params[b];
  const float npinv = -p.y;
  const float npc   = p.x * p.y + 20.0f;
  const float eli = el[row];
  const float* erb = er + (b << 10);
  const float* wb  = w + (b << 10);
  float* fcrow = fc2 + (size_t)row * NN;
  float s = 0.f;
  for (int j = lane * 4; j < NN; j += 256) {
    float4 e4 = *(const float4*)&erb[j];
    float4 w4 = *(const float4*)&wb[j];
    float4 a;
    a.x = __builtin_amdgcn_rcpf(1.0f + __expf(fmaf(leakyf(eli + e4.x), npinv, npc)));
    a.y = __builtin_amdgcn_rcpf(1.0f + __expf(fmaf(leakyf(eli + e4.y), npinv, npc)));
    a.z = __builtin_amdgcn_rcpf(1.0f + __expf(fmaf(leakyf(eli + e4.z), npinv, npc)));
    a.w = __builtin_amdgcn_rcpf(1.0f + __expf(fmaf(leakyf(eli + e4.w), npinv, npc)));
    s += w4.x * a.x + w4.y * a.y + w4.z * a.z + w4.w * a.w;
    *(float4*)&fcrow[j] = a;
  }
#pragma unroll
  for (int off = 32; off > 0; off >>= 1) s += __shfl_down(s, off);
  if (lane == 0) out[row] = leakyf(s + bg[0]);
}

extern "C" void kernel_launch(void* const* d_in, const int* in_sizes, int n_in,
                              void* d_out, int out_size, void* d_ws, size_t ws_size,
                              hipStream_t stream) {
  (void)in_sizes; (void)n_in; (void)out_size; (void)ws_size;
  const float* x  = (const float*)d_in[0];
  const float* W1 = (const float*)d_in[2];
  const float* a1 = (const float*)d_in[3];
  const float* W2 = (const float*)d_in[4];
  const float* a2 = (const float*)d_in[5];
  const float* Wg = (const float*)d_in[6];
  const float* bg = (const float*)d_in[7];

  float* out = (float*)d_out;               // [B,N,1]   32768
  float* fc2 = out + 32768;                 // [B,N,N]   33554432
  float* g2  = fc2 + 33554432;              // [B,N,H2]  4194304

  // Scratch inside the fc2 region (fc2 is written LAST, by final_out_fc2).
  ushort_t* h1Thi = (ushort_t*)fc2;                     // [512][256][64] tiled
  ushort_t* h1Tlo = (ushort_t*)(fc2 + 4194304);
  float*    g1    = fc2 + 8388608;                      // [32768][256] fp32
  ushort_t* h2Thi = (ushort_t*)(fc2 + 16777216);        // [512][128][64] tiled
  ushort_t* h2Tlo = (ushort_t*)(fc2 + 18874368);

  float* wsf = (float*)d_ws;
  float* el1 = wsf;                          // 32768 each; el1,er1,el2,er2,wv
  float* er1 = wsf + 32768;                  //   contiguous -> single memset
  float* el2 = wsf + 65536;
  float* er2 = wsf + 98304;
  float* wv  = wsf + 131072;
  float2* p1 = (float2*)(wsf + 163840);      // 32 float2
  float2* p2 = (float2*)(wsf + 163904);
  ushort_t* W1Thi = (ushort_t*)(wsf + 163968);   // [256][512]
  ushort_t* W1Tlo = (ushort_t*)(wsf + 229504);
  ushort_t* W2Thi = (ushort_t*)(wsf + 295040);   // [128][256]
  ushort_t* W2Tlo = (ushort_t*)(wsf + 311424);

  dim3 blk(256);
  hipMemsetAsync(wsf, 0, 5u * 32768u * sizeof(float), stream);   // el/er/wv = 0
  transpose_w_split<<<512, blk, 0, stream>>>(W1, W1Thi, W1Tlo, HH1, 9);
  transpose_w_split<<<128, blk, 0, stream>>>(W2, W2Thi, W2Tlo, HH2, 8);
  // Stage 1
  gemm_asplit<HH1, 128><<<dim3(512, 2), blk, 0, stream>>>(x, W1Thi, W1Tlo, a1,
                                                          h1Thi, h1Tlo, el1, er1, FIN);
  minmax_params<<<32, blk, 0, stream>>>(el1, er1, p1);
  gemm_att2<128><<<dim3(16, 2, 32), blk, 0, stream>>>(el1, er1, p1, h1Thi, h1Tlo,
                                                      g1, nullptr, nullptr, HH1, 1);
  // Stage 2
  gemm_asplit<HH2, 64><<<dim3(512, 2), blk, 0, stream>>>(g1, W2Thi, W2Tlo, a2,
                                                         h2Thi, h2Tlo, el2, er2, HH1);
  minmax_params<<<32, blk, 0, stream>>>(el2, er2, p2);
  gemm_att2<64><<<dim3(16, 2, 32), blk, 0, stream>>>(el2, er2, p2, h2Thi, h2Tlo,
                                                     g2, Wg, wv, HH2, 0);
  // Stage 3: fc2 + out (att recomputed on the fly; wv = g2 @ Wg already fused)
  final_out_fc2<<<8192, blk, 0, stream>>>(el2, er2, p2, wv, bg, fc2, out);
}

// Round 5
// 476.318 us; speedup vs baseline: 1.0893x; 1.0179x over previous
//
#include <hip/hip_runtime.h>

#define NN 1024
#define FIN 512
#define HH1 256
#define HH2 128
#define MTOT 32768   // B*N total rows

typedef unsigned short ushort_t;
using bf16x8 = __attribute__((ext_vector_type(8))) short;
using f32x4  = __attribute__((ext_vector_type(4))) float;

__device__ __forceinline__ float leakyf(float x) { return fmaxf(x, 0.01f * x); }
__device__ __forceinline__ float eluf(float x) { return x > 0.0f ? x : __expf(x) - 1.0f; }
// pack the high halves of two fp32 bit patterns: [u1.hi : u0.hi]
__device__ __forceinline__ unsigned pack_hi(unsigned u0, unsigned u1) {
  return __builtin_amdgcn_perm(u1, u0, 0x07060302u);
}
// trunc-split two fp32 -> bf16 hi pair + bf16 lo pair (lo compensates hi trunc)
__device__ __forceinline__ void split_pack2(float f0, float f1, unsigned& hp, unsigned& lp) {
  unsigned u0 = __float_as_uint(f0), u1 = __float_as_uint(f1);
  hp = pack_hi(u0, u1);
  float l0 = f0 - __uint_as_float(u0 & 0xFFFF0000u);
  float l1 = f1 - __uint_as_float(u1 & 0xFFFF0000u);
  lp = pack_hi(__float_as_uint(l0), __float_as_uint(l1));
}
// RNE-round two fp32 to bf16 and pack
__device__ __forceinline__ unsigned pack_rne(float f0, float f1) {
  unsigned u0 = __float_as_uint(f0); u0 += 0x7FFFu + ((u0 >> 16) & 1u);
  unsigned u1 = __float_as_uint(f1); u1 += 0x7FFFu + ((u1 >> 16) & 1u);
  return pack_hi(u0, u1);
}

// Raw workgroup barrier WITHOUT the __syncthreads vmcnt(0) drain.
// sbar(): execution sync only (safe when prior LDS reads are already consumed).
// lgkm0_sbar(): flush own ds_writes (lgkm) then sync; global loads STAY IN
// FLIGHT across it — the whole point (T3/T4 counted-vmcnt discipline).
__device__ __forceinline__ void sbar() {
  asm volatile("" ::: "memory");
  __builtin_amdgcn_s_barrier();
  asm volatile("" ::: "memory");
}
__device__ __forceinline__ void lgkm0_sbar() {
  asm volatile("s_waitcnt lgkmcnt(0)" ::: "memory");
  __builtin_amdgcn_s_barrier();
  asm volatile("" ::: "memory");
}

// ---------------------------------------------------------------------------
// W[K][N] fp32 -> WT[N][K] trunc-split bf16. K = 1<<kshift.
// ---------------------------------------------------------------------------
__global__ __launch_bounds__(256) void transpose_w_split(const float* __restrict__ W,
                                                         ushort_t* __restrict__ WThi,
                                                         ushort_t* __restrict__ WTlo,
                                                         int Nc, int kshift) {
  int idx = blockIdx.x * 256 + threadIdx.x;
  int k = idx & ((1 << kshift) - 1);
  int n = idx >> kshift;
  float f = W[(size_t)k * Nc + n];
  unsigned u = __float_as_uint(f);
  WThi[idx] = (ushort_t)(u >> 16);
  float lo = f - __uint_as_float(u & 0xFFFF0000u);
  WTlo[idx] = (ushort_t)(__float_as_uint(lo) >> 16);
}

// ---------------------------------------------------------------------------
// Producer GEMM, full split precision (3 MFMA): C = A(fp32)[M,K] @ B, with
// B transposed split BT[NC][K]. Block tile 64 x NCB; gridDim.y = NC/NCB.
// K-loop sync uses raw barriers: barrier A (exec-only) before LDS writes,
// barrier B (lgkm flush only) after — next-tile global loads are issued
// between the writes and barrier B and REMAIN IN FLIGHT across the barrier
// and the MFMA cluster (the old __syncthreads vmcnt(0) drain was the
// structural stall: all pipes <25% busy, occupancy-insensitive).
// Outputs: CT split, tile-blocked CT_t[tile=M/64][NC][64]; el/er partial row
// dots atomicAdd'ed across n-blocks (pre-zeroed).
// ---------------------------------------------------------------------------
template<int NC, int NCB>
__global__ __launch_bounds__(256, 4) void gemm_asplit(const float* __restrict__ A,
                                                      const ushort_t* __restrict__ BThi,
                                                      const ushort_t* __restrict__ BTlo,
                                                      const float* __restrict__ avec,
                                                      ushort_t* __restrict__ CThi,
                                                      ushort_t* __restrict__ CTlo,
                                                      float* __restrict__ el,
                                                      float* __restrict__ er, int K) {
  constexpr int NFR = NCB / 32;   // n-frags per wave (wave tile 32 x NCB/2)
  constexpr int NB  = NCB / 64;   // 16B B-chunks per thread per buffer
  __shared__ ushort_t Ah[64 * 40], Al[64 * 40];
  __shared__ ushort_t Bbuf[NCB * 80];      // Bh | Bl during loop; stg after
  __shared__ float aL[NCB], aR[NCB];
  ushort_t* Bh = Bbuf;
  ushort_t* Bl = Bbuf + NCB * 40;
  const int t = threadIdx.x, lane = t & 63, wid = t >> 6;
  const int wm = (wid & 1) * 32, wn = (wid >> 1) * (NCB / 2);
  const int ln = lane & 15, quad = lane >> 4;
  const int m0 = blockIdx.x * 64;
  const int n0c = blockIdx.y * NCB;
  if (t < NCB) { aL[t] = avec[n0c + t]; aR[t] = avec[NC + n0c + t]; }
  const int ra = t >> 2, ka = (t & 3) * 8;
  const float* ap = A + (size_t)(m0 + ra) * K + ka;
  const int brow = (t >> 2);            // + i*64 per chunk
  const int bko  = (t & 3) * 8;
  f32x4 acc[2][NFR];
#pragma unroll
  for (int mi = 0; mi < 2; ++mi)
#pragma unroll
    for (int ni = 0; ni < NFR; ++ni) acc[mi][ni] = (f32x4){0.f, 0.f, 0.f, 0.f};

  // ---- prologue: loads for tile k0=0
  float4 fa0 = *(const float4*)(ap);
  float4 fa1 = *(const float4*)(ap + 4);
  uint4 vbh[NB], vbl[NB];
#pragma unroll
  for (int i = 0; i < NB; ++i) {
    size_t off = (size_t)(n0c + brow + i * 64) * K + bko;
    vbh[i] = *(const uint4*)&BThi[off];
    vbl[i] = *(const uint4*)&BTlo[off];
  }

  for (int k0 = 0; k0 < K; k0 += 32) {
    uint4 ah4, al4;
    split_pack2(fa0.x, fa0.y, ah4.x, al4.x);
    split_pack2(fa0.z, fa0.w, ah4.y, al4.y);
    split_pack2(fa1.x, fa1.y, ah4.z, al4.z);
    split_pack2(fa1.z, fa1.w, ah4.w, al4.w);
    sbar();   // prior-step LDS reads are consumed; safe to overwrite
    *(uint4*)&Ah[ra * 40 + ka] = ah4;
    *(uint4*)&Al[ra * 40 + ka] = al4;
#pragma unroll
    for (int i = 0; i < NB; ++i) {
      *(uint4*)&Bh[(brow + i * 64) * 40 + bko] = vbh[i];
      *(uint4*)&Bl[(brow + i * 64) * 40 + bko] = vbl[i];
    }
    // issue next-tile global loads; they stay in flight across barrier B
    const int kn = (k0 + 32 < K) ? (k0 + 32) : 0;
    fa0 = *(const float4*)(ap + kn);
    fa1 = *(const float4*)(ap + kn + 4);
#pragma unroll
    for (int i = 0; i < NB; ++i) {
      size_t off = (size_t)(n0c + brow + i * 64) * K + kn + bko;
      vbh[i] = *(const uint4*)&BThi[off];
      vbl[i] = *(const uint4*)&BTlo[off];
    }
    lgkm0_sbar();   // ds_writes visible; vm NOT drained
    bf16x8 ahf[2], alf[2], bhf[NFR], blf[NFR];
#pragma unroll
    for (int i = 0; i < 2; ++i) {
      const int ao = (wm + i * 16 + ln) * 40 + quad * 8;
      ahf[i] = *(const bf16x8*)&Ah[ao];
      alf[i] = *(const bf16x8*)&Al[ao];
    }
#pragma unroll
    for (int i = 0; i < NFR; ++i) {
      const int bo = (wn + i * 16 + ln) * 40 + quad * 8;
      bhf[i] = *(const bf16x8*)&Bh[bo];
      blf[i] = *(const bf16x8*)&Bl[bo];
    }
#pragma unroll
    for (int mi = 0; mi < 2; ++mi)
#pragma unroll
      for (int ni = 0; ni < NFR; ++ni) {
        acc[mi][ni] = __builtin_amdgcn_mfma_f32_16x16x32_bf16(ahf[mi], bhf[ni], acc[mi][ni], 0, 0, 0);
        acc[mi][ni] = __builtin_amdgcn_mfma_f32_16x16x32_bf16(ahf[mi], blf[ni], acc[mi][ni], 0, 0, 0);
        acc[mi][ni] = __builtin_amdgcn_mfma_f32_16x16x32_bf16(alf[mi], bhf[ni], acc[mi][ni], 0, 0, 0);
      }
  }

  // ---- el/er partial row-dot reduction over this block's NCB cols ----
#pragma unroll
  for (int mi = 0; mi < 2; ++mi) {
    const int mr = m0 + wm + mi * 16 + quad * 4;
#pragma unroll
    for (int rr = 0; rr < 4; ++rr) {
      float vel = 0.f, ver = 0.f;
#pragma unroll
      for (int ni = 0; ni < NFR; ++ni) {
        const int c = wn + ni * 16 + ln;
        vel = fmaf(acc[mi][ni][rr], aL[c], vel);
        ver = fmaf(acc[mi][ni][rr], aR[c], ver);
      }
#pragma unroll
      for (int m = 1; m < 16; m <<= 1) {
        vel += __shfl_xor(vel, m);
        ver += __shfl_xor(ver, m);
      }
      if (ln == 0) {
        atomicAdd(&el[mr + rr], vel);
        atomicAdd(&er[mr + rr], ver);
      }
    }
  }

  // ---- staged CT write, tile-blocked: contiguous [NCB][64] slice ----
  // stg layout: [NCB cols][66 rows-padded] ushort, overlaid on Bbuf.
  ushort_t* dsthi = CThi + (size_t)blockIdx.x * (NC * 64) + (size_t)n0c * 64;
  ushort_t* dstlo = CTlo + (size_t)blockIdx.x * (NC * 64) + (size_t)n0c * 64;
  const int colbase = wid * (NCB / 4);
  const int g = lane >> 2, j = lane & 3;
#pragma unroll
  for (int pass = 0; pass < 2; ++pass) {
    __syncthreads();   // loop ds_reads (pass 0) / prev-pass stg reads (pass 1) done
#pragma unroll
    for (int mi = 0; mi < 2; ++mi) {
      const int rbase = wm + mi * 16 + quad * 4;
#pragma unroll
      for (int ni = 0; ni < NFR; ++ni) {
        const int c = wn + ni * 16 + ln;
        unsigned h01, l01, h23, l23;
        split_pack2(acc[mi][ni][0], acc[mi][ni][1], h01, l01);
        split_pack2(acc[mi][ni][2], acc[mi][ni][3], h23, l23);
        uint2 v = pass ? make_uint2(l01, l23) : make_uint2(h01, h23);
        *(uint2*)&Bbuf[c * 66 + rbase] = v;
      }
    }
    __syncthreads();
    ushort_t* dst = pass ? dstlo : dsthi;
#pragma unroll
    for (int cc = 0; cc < NCB / 64; ++cc) {
      const int col = colbase + cc * 16 + g;
#pragma unroll
      for (int half = 0; half < 2; ++half) {
        const int r = half * 32 + j * 8;
        *(uint4*)&dst[col * 64 + r] = *(const uint4*)&Bbuf[col * 66 + r];
      }
    }
  }
}

// Per-batch min/max of el, er -> (mn, 30/(mx-mn)); leaky is monotone.
__global__ __launch_bounds__(256) void minmax_params(const float* __restrict__ el,
                                                     const float* __restrict__ er,
                                                     float2* __restrict__ params) {
  __shared__ float smnl[256], smxl[256], smnr[256], smxr[256];
  const int b = blockIdx.x, t = threadIdx.x;
  float mnl = 3.4e38f, mxl = -3.4e38f, mnr = 3.4e38f, mxr = -3.4e38f;
  for (int i = t; i < NN; i += 256) {
    float v = el[b * NN + i];
    mnl = fminf(mnl, v); mxl = fmaxf(mxl, v);
    float u = er[b * NN + i];
    mnr = fminf(mnr, u); mxr = fmaxf(mxr, u);
  }
  smnl[t] = mnl; smxl[t] = mxl; smnr[t] = mnr; smxr[t] = mxr;
  __syncthreads();
  for (int s = 128; s > 0; s >>= 1) {
    if (t < s) {
      smnl[t] = fminf(smnl[t], smnl[t + s]);
      smxl[t] = fmaxf(smxl[t], smxl[t + s]);
      smnr[t] = fminf(smnr[t], smnr[t + s]);
      smxr[t] = fmaxf(smxr[t], smxr[t + s]);
    }
    __syncthreads();
  }
  if (t == 0) {
    float mn = leakyf(smnl[0] + smnr[0]);
    float mx = leakyf(smxl[0] + smxr[0]);
    params[b] = make_float2(mn, 30.0f / (mx - mn));
  }
}

// ---------------------------------------------------------------------------
// Attention MFMA GEMM: C[i,f] = sum_j att(i,j)*h[j,f]. att synthesized fp32,
// RNE bf16 hi-only A-operand; h split B-operand (2 MFMA). Block 64 x BW,
// gridDim.y = Nc/BW. h is in TILE-BLOCKED layout CT_t[tile][Nc][64].
// Same raw-barrier K-loop as gemm_asplit (loads in flight across barriers).
// doElu: stage-1 epilogue. wg!=null: fuse wv[row] += sum_{f in block} C*wg[f].
// ---------------------------------------------------------------------------
template<int BW>
__global__ __launch_bounds__(256, 4) void gemm_att2(const float* __restrict__ el,
                                                    const float* __restrict__ er,
                                                    const float2* __restrict__ params,
                                                    const ushort_t* __restrict__ hThi,
                                                    const ushort_t* __restrict__ hTlo,
                                                    float* __restrict__ C,
                                                    const float* __restrict__ wg,
                                                    float* __restrict__ wv,
                                                    int Nc, int doElu) {
  constexpr int NFR = BW / 32;
  __shared__ ushort_t Ah[64 * 40];
  __shared__ ushort_t Bh[BW * 40], Bl[BW * 40];
  __shared__ float ers[NN];
  __shared__ float wls[BW];
  const int b = blockIdx.z, t = threadIdx.x, lane = t & 63, wid = t >> 6;
  const int wm = (wid & 1) * 32, wn = (wid >> 1) * (BW / 2);
  const int ln = lane & 15, quad = lane >> 4;
  const int m0 = blockIdx.x * 64, n0 = blockIdx.y * BW;
  const float2 p = params[b];
  const float npinv = -p.y;                  // q = exp(-e_s)
  const float npc   = p.x * p.y + 20.0f;
  *(float4*)&ers[t * 4] = *(const float4*)&er[b * NN + t * 4];
  if (wg && t < BW) wls[t] = wg[n0 + t];
  const int ra = t >> 2, ka = (t & 3) * 8;
  const float elv = el[b * NN + m0 + ra];
  // B loader geometry: BW=128 -> 2 uint4/thread/buf; BW=64 -> 1 uint4.
  const int rb = (BW == 128) ? (t >> 1) : (t >> 2);
  const int kb = (BW == 128) ? ((t & 1) * 16) : ((t & 3) * 8);
  const size_t tstride = (size_t)Nc * 64;                 // ushorts per tile
  const size_t rowoff  = (size_t)(n0 + rb) * 64 + kb;     // within tile
  f32x4 acc[2][NFR];
#pragma unroll
  for (int mi = 0; mi < 2; ++mi)
#pragma unroll
    for (int ni = 0; ni < NFR; ++ni) acc[mi][ni] = (f32x4){0.f, 0.f, 0.f, 0.f};
  __syncthreads();   // ers/wls visible

  // ---- prologue: loads for tile k0=0
  uint4 vbh0, vbl0, vbh1, vbl1;
  {
    const size_t toff = (size_t)(b * 16) * tstride + rowoff;
    vbh0 = *(const uint4*)&hThi[toff];
    vbl0 = *(const uint4*)&hTlo[toff];
    if constexpr (BW == 128) {
      vbh1 = *(const uint4*)&hThi[toff + 8];
      vbl1 = *(const uint4*)&hTlo[toff + 8];
    }
  }

  for (int k0 = 0; k0 < NN; k0 += 32) {
    float s[8];
#pragma unroll
    for (int j = 0; j < 8; ++j) {
      float x = elv + ers[k0 + ka + j];
      x = fmaxf(x, 0.01f * x);
      s[j] = __builtin_amdgcn_rcpf(1.0f + __expf(fmaf(x, npinv, npc)));
    }
    uint4 av;
    av.x = pack_rne(s[0], s[1]); av.y = pack_rne(s[2], s[3]);
    av.z = pack_rne(s[4], s[5]); av.w = pack_rne(s[6], s[7]);
    sbar();   // prior-step LDS reads consumed; safe to overwrite
    *(uint4*)&Ah[ra * 40 + ka] = av;
    *(uint4*)&Bh[rb * 40 + kb] = vbh0;
    *(uint4*)&Bl[rb * 40 + kb] = vbl0;
    if constexpr (BW == 128) {
      *(uint4*)&Bh[rb * 40 + kb + 8] = vbh1;
      *(uint4*)&Bl[rb * 40 + kb + 8] = vbl1;
    }
    // issue next-tile loads; in flight across barrier B + MFMA cluster
    const int kn = (k0 + 32 < NN) ? (k0 + 32) : 0;
    {
      const size_t toff = (size_t)(b * 16 + (kn >> 6)) * tstride + (size_t)(kn & 32) + rowoff;
      vbh0 = *(const uint4*)&hThi[toff];
      vbl0 = *(const uint4*)&hTlo[toff];
      if constexpr (BW == 128) {
        vbh1 = *(const uint4*)&hThi[toff + 8];
        vbl1 = *(const uint4*)&hTlo[toff + 8];
      }
    }
    lgkm0_sbar();   // ds_writes visible; vm NOT drained
    bf16x8 af[2], bhf[NFR], blf[NFR];
#pragma unroll
    for (int i = 0; i < 2; ++i) af[i] = *(const bf16x8*)&Ah[(wm + i * 16 + ln) * 40 + quad * 8];
#pragma unroll
    for (int i = 0; i < NFR; ++i) {
      const int bo = (wn + i * 16 + ln) * 40 + quad * 8;
      bhf[i] = *(const bf16x8*)&Bh[bo];
      blf[i] = *(const bf16x8*)&Bl[bo];
    }
#pragma unroll
    for (int mi = 0; mi < 2; ++mi)
#pragma unroll
      for (int ni = 0; ni < NFR; ++ni) {
        acc[mi][ni] = __builtin_amdgcn_mfma_f32_16x16x32_bf16(af[mi], bhf[ni], acc[mi][ni], 0, 0, 0);
        acc[mi][ni] = __builtin_amdgcn_mfma_f32_16x16x32_bf16(af[mi], blf[ni], acc[mi][ni], 0, 0, 0);
      }
  }
#pragma unroll
  for (int mi = 0; mi < 2; ++mi) {
    const int mrl = m0 + wm + mi * 16 + quad * 4;         // row within batch
    const size_t mrow = (size_t)b * NN + mrl;
#pragma unroll
    for (int ni = 0; ni < NFR; ++ni) {
      const int c = n0 + wn + ni * 16 + ln;
#pragma unroll
      for (int rr = 0; rr < 4; ++rr) {
        float v = acc[mi][ni][rr];
        if (doElu) v = eluf(v);
        C[(mrow + rr) * Nc + c] = v;
      }
    }
    if (wg) {
#pragma unroll
      for (int rr = 0; rr < 4; ++rr) {
        float vw = 0.f;
#pragma unroll
        for (int ni = 0; ni < NFR; ++ni)
          vw = fmaf(acc[mi][ni][rr], wls[wn + ni * 16 + ln], vw);
#pragma unroll
        for (int m = 1; m < 16; m <<= 1) vw += __shfl_xor(vw, m);
        if (ln == 0) atomicAdd(&wv[b * NN + mrl + rr], vw);
      }
    }
  }
}

// ---------------------------------------------------------------------------
// Fused: fc2[b,i,j] = att2(i,j) (fp32) AND out[b,i] = leaky(sum_j att*w + bg).
// One wave per row i; lanes cover 4 consecutive j each (coalesced float4).
// ---------------------------------------------------------------------------
__global__ __launch_bounds__(256) void final_out_fc2(const float* __restrict__ el,
                                                     const float* __restrict__ er,
                                                     const float2* __restrict__ params,
                                                     const float* __restrict__ w,
                                                     const float* __restrict__ bg,
                                                     float* __restrict__ fc2,
                                                     float* __restrict__ out) {
  const int row  = (blockIdx.x * 256 + threadIdx.x) >> 6;  // b*N+i
  const int lane = threadIdx.x & 63;
  const int b = row >> 10;
  const float2 p = params[b];
  const float npinv = -p.y;
  const float npc   = p.x * p.y + 20.0f;
  const float eli = el[row];
  const float* erb = er + (b << 10);
  const float* wb  = w + (b << 10);
  float* fcrow = fc2 + (size_t)row * NN;
  float s = 0.f;
  for (int j = lane * 4; j < NN; j += 256) {
    float4 e4 = *(const float4*)&erb[j];
    float4 w4 = *(const float4*)&wb[j];
    float4 a;
    a.x = __builtin_amdgcn_rcpf(1.0f + __expf(fmaf(leakyf(eli + e4.x), npinv, npc)));
    a.y = __builtin_amdgcn_rcpf(1.0f + __expf(fmaf(leakyf(eli + e4.y), npinv, npc)));
    a.z = __builtin_amdgcn_rcpf(1.0f + __expf(fmaf(leakyf(eli + e4.z), npinv, npc)));
    a.w = __builtin_amdgcn_rcpf(1.0f + __expf(fmaf(leakyf(eli + e4.w), npinv, npc)));
    s += w4.x * a.x + w4.y * a.y + w4.z * a.z + w4.w * a.w;
    *(float4*)&fcrow[j] = a;
  }
#pragma unroll
  for (int off = 32; off > 0; off >>= 1) s += __shfl_down(s, off);
  if (lane == 0) out[row] = leakyf(s + bg[0]);
}

extern "C" void kernel_launch(void* const* d_in, const int* in_sizes, int n_in,
                              void* d_out, int out_size, void* d_ws, size_t ws_size,
                              hipStream_t stream) {
  (void)in_sizes; (void)n_in; (void)out_size; (void)ws_size;
  const float* x  = (const float*)d_in[0];
  const float* W1 = (const float*)d_in[2];
  const float* a1 = (const float*)d_in[3];
  const float* W2 = (const float*)d_in[4];
  const float* a2 = (const float*)d_in[5];
  const float* Wg = (const float*)d_in[6];
  const float* bg = (const float*)d_in[7];

  float* out = (float*)d_out;               // [B,N,1]   32768
  float* fc2 = out + 32768;                 // [B,N,N]   33554432
  float* g2  = fc2 + 33554432;              // [B,N,H2]  4194304

  // Scratch inside the fc2 region (fc2 is written LAST, by final_out_fc2).
  ushort_t* h1Thi = (ushort_t*)fc2;                     // [512][256][64] tiled
  ushort_t* h1Tlo = (ushort_t*)(fc2 + 4194304);
  float*    g1    = fc2 + 8388608;                      // [32768][256] fp32
  ushort_t* h2Thi = (ushort_t*)(fc2 + 16777216);        // [512][128][64] tiled
  ushort_t* h2Tlo = (ushort_t*)(fc2 + 18874368);

  float* wsf = (float*)d_ws;
  float* el1 = wsf;                          // 32768 each; el1,er1,el2,er2,wv
  float* er1 = wsf + 32768;                  //   contiguous -> single memset
  float* el2 = wsf + 65536;
  float* er2 = wsf + 98304;
  float* wv  = wsf + 131072;
  float2* p1 = (float2*)(wsf + 163840);      // 32 float2
  float2* p2 = (float2*)(wsf + 163904);
  ushort_t* W1Thi = (ushort_t*)(wsf + 163968);   // [256][512]
  ushort_t* W1Tlo = (ushort_t*)(wsf + 229504);
  ushort_t* W2Thi = (ushort_t*)(wsf + 295040);   // [128][256]
  ushort_t* W2Tlo = (ushort_t*)(wsf + 311424);

  dim3 blk(256);
  hipMemsetAsync(wsf, 0, 5u * 32768u * sizeof(float), stream);   // el/er/wv = 0
  transpose_w_split<<<512, blk, 0, stream>>>(W1, W1Thi, W1Tlo, HH1, 9);
  transpose_w_split<<<128, blk, 0, stream>>>(W2, W2Thi, W2Tlo, HH2, 8);
  // Stage 1
  gemm_asplit<HH1, 128><<<dim3(512, 2), blk, 0, stream>>>(x, W1Thi, W1Tlo, a1,
                                                          h1Thi, h1Tlo, el1, er1, FIN);
  minmax_params<<<32, blk, 0, stream>>>(el1, er1, p1);
  gemm_att2<128><<<dim3(16, 2, 32), blk, 0, stream>>>(el1, er1, p1, h1Thi, h1Tlo,
                                                      g1, nullptr, nullptr, HH1, 1);
  // Stage 2
  gemm_asplit<HH2, 64><<<dim3(512, 2), blk, 0, stream>>>(g1, W2Thi, W2Tlo, a2,
                                                         h2Thi, h2Tlo, el2, er2, HH1);
  minmax_params<<<32, blk, 0, stream>>>(el2, er2, p2);
  gemm_att2<64><<<dim3(16, 2, 32), blk, 0, stream>>>(el2, er2, p2, h2Thi, h2Tlo,
                                                     g2, Wg, wv, HH2, 0);
  // Stage 3: fc2 + out (att recomputed on the fly; wv = g2 @ Wg already fused)
  final_out_fc2<<<8192, blk, 0, stream>>>(el2, er2, p2, wv, bg, fc2, out);
}